// Round 12
// baseline (1974.178 us; speedup 1.0000x reference)
//
#include <hip/hip_runtime.h>
#include <math.h>

#define H 128
#define H2 256
#define LDC 136   // LDS row stride (bf16) for conv weight rows (128 k)
#define LDK 72    // LDS row stride (bf16) for 64-wide k rows (ffn_fused)
#define LDHW 136  // LDS row stride (bf16) for per-wave hidden half (ffn_fused)
#define FFN_SMEM (H2 * LDK)  // 18432 shorts = 36864 B -> 4 blocks/CU
// persistent FFN LDS layout (shorts):
//   W1s: [256][136]  = 34816          (rows: hidden col n, 128 k + pad8)
//   W2s: [128][264]  = 33792 @34816   (rows: out col c, 256 k + pad8)
//   scr: 16 waves x [16][40] = 10240 @68608  (per-wave transpose buffer)
// total 78848 shorts = 157696 B  (<= 160 KiB/CU, 1 block/CU, 16 waves)
// REG DISCIPLINE (round-3/6): 128 unified VGPR+AGPR/wave at 16 waves/CU.
// TILE MAPPING (round-8): grid-stride keeps HBM channel interleave even.
// X-PRECISION (round-10/11): bf16 x carrier; accuracy fine (absmax 20.5),
// but 2-byte scalar epilogue I/O caused ~6x sector amplification (WRITE
// 150MB vs 26 logical) regardless of loop order.
// EPILOGUE (round-12): route C-writes and residual reads through the
// per-wave LDS transpose so all global I/O is short8 (16B/lane, 16 rows x
// 64B contiguous per instruction) — identical shape to the A-load, which
// shows no amplification. Pooling via post-transpose shfl row-reduce.

typedef __attribute__((ext_vector_type(8))) short short8;
typedef __attribute__((ext_vector_type(4))) float floatx4;

// fast GELU: x * sigmoid(1.5957691*x*(1+0.044715*x^2)); max |dev| from exact erf-GELU ~1e-3
__device__ __forceinline__ float gelu_f(float x) {
  float t = 1.59576912161f * x * fmaf(0.044715f, x * x, 1.0f);
  return x / (1.0f + __expf(-t));
}

__device__ __forceinline__ unsigned short f2b(float f) {
  union { float f; unsigned u; } c; c.f = f;
  unsigned r = c.u + 0x7fffu + ((c.u >> 16) & 1u);
  return (unsigned short)(r >> 16);
}

__device__ __forceinline__ float b2f(unsigned short u) {
  union { unsigned u; float f; } c; c.u = ((unsigned)u) << 16; return c.f;
}

__device__ __forceinline__ float blo(unsigned u) { return __uint_as_float(u << 16); }
__device__ __forceinline__ float bhi(unsigned u) { return __uint_as_float(u & 0xffff0000u); }

__device__ __forceinline__ short8 pack8(floatx4 a, floatx4 b) {
  union { short8 v; unsigned short s[8]; } u;
  u.s[0] = f2b(a.x); u.s[1] = f2b(a.y); u.s[2] = f2b(a.z); u.s[3] = f2b(a.w);
  u.s[4] = f2b(b.x); u.s[5] = f2b(b.y); u.s[6] = f2b(b.z); u.s[7] = f2b(b.w);
  return u.v;
}

__device__ __forceinline__ void unpack8(short8 s, floatx4& a, floatx4& b) {
  union { short8 v; unsigned short u[8]; } c; c.v = s;
  a.x = b2f(c.u[0]); a.y = b2f(c.u[1]); a.z = b2f(c.u[2]); a.w = b2f(c.u[3]);
  b.x = b2f(c.u[4]); b.y = b2f(c.u[5]); b.z = b2f(c.u[6]); b.w = b2f(c.u[7]);
}

// ---------------- weight transpose+convert: W[b][K][N] fp32 -> WT[b][N][K] bf16 ----------------
__global__ __launch_bounds__(256) void transpose_w(const float* __restrict__ W, unsigned short* __restrict__ WT,
                                                   int K, int Ncol, int total) {
  int i = blockIdx.x * 256 + threadIdx.x;
  if (i >= total) return;
  int kn = K * Ncol;
  int b = i / kn, r = i - b * kn;
  int k = r / Ncol, n = r - k * Ncol;
  WT[b * kn + n * K + k] = f2b(W[i]);
}

// ---------------- CSR build ----------------

__global__ __launch_bounds__(256) void hist_kernel(int* __restrict__ cnt, const int* __restrict__ dst, int E) {
  int i = blockIdx.x * 256 + threadIdx.x;
  if (i < E) atomicAdd(&cnt[dst[i]], 1);
}

__global__ __launch_bounds__(256) void scan_a(const int* __restrict__ cnt, int* __restrict__ row_ptr,
                                              int* __restrict__ blockSum, float* __restrict__ dinv, int N) {
  __shared__ int ls[256];
  int t = threadIdx.x;
  int idx = blockIdx.x * 1024 + t * 4;
  int4 v = make_int4(0, 0, 0, 0);
  if (idx + 3 < N) v = *(const int4*)&cnt[idx];
  else {
    if (idx + 0 < N) v.x = cnt[idx + 0];
    if (idx + 1 < N) v.y = cnt[idx + 1];
    if (idx + 2 < N) v.z = cnt[idx + 2];
    if (idx + 3 < N) v.w = cnt[idx + 3];
  }
  if (idx + 0 < N) dinv[idx + 0] = rsqrtf((float)v.x + 1.0f);
  if (idx + 1 < N) dinv[idx + 1] = rsqrtf((float)v.y + 1.0f);
  if (idx + 2 < N) dinv[idx + 2] = rsqrtf((float)v.z + 1.0f);
  if (idx + 3 < N) dinv[idx + 3] = rsqrtf((float)v.w + 1.0f);
  int s = v.x + v.y + v.z + v.w;
  ls[t] = s;
  __syncthreads();
  for (int off = 1; off < 256; off <<= 1) {
    int a = (t >= off) ? ls[t - off] : 0;
    __syncthreads();
    ls[t] += a;
    __syncthreads();
  }
  int p = ls[t] - s;
  if (t == 255) blockSum[blockIdx.x] = ls[255];
  if (idx + 0 < N) row_ptr[idx + 0] = p;  p += v.x;
  if (idx + 1 < N) row_ptr[idx + 1] = p;  p += v.y;
  if (idx + 2 < N) row_ptr[idx + 2] = p;  p += v.z;
  if (idx + 3 < N) row_ptr[idx + 3] = p;
}

__global__ __launch_bounds__(1024) void scan_b(const int* __restrict__ blockSum, int* __restrict__ blockOff,
                                               int nb, int* __restrict__ row_ptr, int N, int E) {
  __shared__ int ls[1024];
  int t = threadIdx.x;
  int s = (t < nb) ? blockSum[t] : 0;
  ls[t] = s;
  __syncthreads();
  for (int off = 1; off < 1024; off <<= 1) {
    int a = (t >= off) ? ls[t - off] : 0;
    __syncthreads();
    ls[t] += a;
    __syncthreads();
  }
  if (t < nb) blockOff[t] = ls[t] - s;
  if (t == 0) row_ptr[N] = E;
}

__global__ __launch_bounds__(256) void scan_c(int* __restrict__ row_ptr, const int* __restrict__ blockOff, int N) {
  int t = threadIdx.x;
  int idx = blockIdx.x * 1024 + t * 4;
  int off = blockOff[blockIdx.x];
  if (off == 0) return;
  if (idx + 3 < N) {
    int4 v = *(const int4*)&row_ptr[idx];
    v.x += off; v.y += off; v.z += off; v.w += off;
    *(int4*)&row_ptr[idx] = v;
  } else {
    if (idx + 0 < N) row_ptr[idx + 0] += off;
    if (idx + 1 < N) row_ptr[idx + 1] += off;
    if (idx + 2 < N) row_ptr[idx + 2] += off;
    if (idx + 3 < N) row_ptr[idx + 3] += off;
  }
}

__global__ __launch_bounds__(256) void build_csr_kernel(const int* __restrict__ src, const int* __restrict__ dst,
                                                        const int* __restrict__ row_ptr, int* __restrict__ cursor,
                                                        const float* __restrict__ dinv,
                                                        int* __restrict__ csr_src, float* __restrict__ csr_norm,
                                                        int E) {
  int i = blockIdx.x * 256 + threadIdx.x;
  if (i < E) {
    int s = src[i], d = dst[i];
    int pos = row_ptr[d] + atomicAdd(&cursor[d], 1);
    csr_src[pos] = s;
    csr_norm[pos] = dinv[s] * dinv[d];
  }
}

// ---------------- small setup kernels ----------------

__global__ __launch_bounds__(256) void count_kernel(float* counts, const int* __restrict__ batch, int N, int G) {
  __shared__ float hist[256];
  int t = threadIdx.x;
  if (t < G) hist[t] = 0.f;
  __syncthreads();
  int i0 = (blockIdx.x * 256 + t) * 16;
  int cur = -1; float run = 0.f;
  for (int j = 0; j < 16; j++) {
    int i = i0 + j;
    if (i < N) {
      int b = batch[i];
      if (b == cur) run += 1.f;
      else { if (cur >= 0) atomicAdd(&hist[cur], run); cur = b; run = 1.f; }
    }
  }
  if (cur >= 0) atomicAdd(&hist[cur], run);
  __syncthreads();
  if (t < G && hist[t] != 0.f) atomicAdd(&counts[t], hist[t]);
}

__global__ __launch_bounds__(256) void vn_init_kernel(float* vn, const float* __restrict__ emb, int n) {
  int i = blockIdx.x * 256 + threadIdx.x;
  if (i < n) vn[i] = emb[i & (H - 1)];
}

// ---------------- fused gather aggregation (bf16 h, bf16 x) + BN stats ----------------
// 2 nodes per wave-instruction (half-wave per node, 4 ch/lane). 8 nodes/wave as 4 pairs.
__global__ __launch_bounds__(256) void gather_agg(const unsigned short* __restrict__ h, const int* __restrict__ csr_src,
                                                  const float* __restrict__ csr_norm, const int* __restrict__ row_ptr,
                                                  const float* __restrict__ dinv, const float* __restrict__ vn,
                                                  const int* __restrict__ batch, const float* __restrict__ bias,
                                                  unsigned short* __restrict__ x, float* __restrict__ stats, int N) {
  __shared__ float sred[4 * H];
  __shared__ float qred[4 * H];
  int w = threadIdx.x >> 6, lane = threadIdx.x & 63;
  int hh = lane >> 5;          // which node of the pair
  int li = lane & 31;
  int c = li * 4;              // 4 channels per lane
  floatx4 bi = *(const floatx4*)&bias[c];
  int base = blockIdx.x * 32 + w * 8;

  int nd[4]; bool act[4];
#pragma unroll
  for (int j = 0; j < 4; j++) {
    int n0 = base + 2 * j + hh;
    act[j] = n0 < N;
    nd[j] = act[j] ? n0 : (N - 1);
  }
  int beg[4], end[4], bt[4];
  float dd[4];
#pragma unroll
  for (int j = 0; j < 4; j++) { beg[j] = row_ptr[nd[j]]; end[j] = row_ptr[nd[j] + 1]; }
#pragma unroll
  for (int j = 0; j < 4; j++) { bt[j] = batch[nd[j]]; float di = dinv[nd[j]]; dd[j] = di * di; }
  uint2 xo[4]; uint2 hs[4];
#pragma unroll
  for (int j = 0; j < 4; j++) {
    xo[j] = *(const uint2*)&x[(long)nd[j] * H + c];
    hs[j] = *(const uint2*)&h[(long)nd[j] * H + c];
  }
  float a0[4], a1[4], a2[4], a3[4];
#pragma unroll
  for (int j = 0; j < 4; j++) {
    a0[j] = blo(hs[j].x) * dd[j];
    a1[j] = bhi(hs[j].x) * dd[j];
    a2[j] = blo(hs[j].y) * dd[j];
    a3[j] = bhi(hs[j].y) * dd[j];
  }

#define GROUP_CSR(j, eb, sv, nv)                      \
  int sv; float nv;                                   \
  {                                                   \
    int idx_ = beg[j] + (eb) + li;                    \
    bool vld_ = (li < 8) && (idx_ < end[j]);          \
    int sidx_ = vld_ ? idx_ : 0;                      \
    sv = csr_src[sidx_];                              \
    nv = vld_ ? csr_norm[sidx_] : 0.f;                \
  }

#define GROUP_GACC(j, sv, nv)                         \
  {                                                   \
    uint2 u_[8]; float wg_[8];                        \
    _Pragma("unroll")                                 \
    for (int ii = 0; ii < 8; ii++) {                  \
      wg_[ii] = __shfl(nv, hh * 32 + ii);             \
      int si_ = __shfl(sv, hh * 32 + ii);             \
      u_[ii] = *(const uint2*)&h[(long)si_ * H + c];  \
    }                                                 \
    _Pragma("unroll")                                 \
    for (int ii = 0; ii < 8; ii++) {                  \
      a0[j] += blo(u_[ii].x) * wg_[ii];               \
      a1[j] += bhi(u_[ii].x) * wg_[ii];               \
      a2[j] += blo(u_[ii].y) * wg_[ii];               \
      a3[j] += bhi(u_[ii].y) * wg_[ii];               \
    }                                                 \
  }

  // first edge-group of all 4 pairs: csr loads all issued first
  {
    GROUP_CSR(0, 0, sv0, nv0)
    GROUP_CSR(1, 0, sv1, nv1)
    GROUP_CSR(2, 0, sv2, nv2)
    GROUP_CSR(3, 0, sv3, nv3)
    GROUP_GACC(0, sv0, nv0)
    GROUP_GACC(1, sv1, nv1)
    GROUP_GACC(2, sv2, nv2)
    GROUP_GACC(3, sv3, nv3)
  }

  // tails (deg > 8): interleave needed groups across pairs per round
  int dmx[4];
#pragma unroll
  for (int j = 0; j < 4; j++) {
    int d = end[j] - beg[j];
    int dx = __shfl_xor(d, 32);
    dmx[j] = d > dx ? d : dx;      // wave-uniform per pair
  }
  int dall = dmx[0];
  if (dmx[1] > dall) dall = dmx[1];
  if (dmx[2] > dall) dall = dmx[2];
  if (dmx[3] > dall) dall = dmx[3];
  for (int eb = 8; eb < dall; eb += 8) {
#pragma unroll
    for (int j = 0; j < 4; j++) {
      if (eb < dmx[j]) {
        GROUP_CSR(j, eb, svt, nvt)
        GROUP_GACC(j, svt, nvt)
      }
    }
  }
#undef GROUP_CSR
#undef GROUP_GACC

  // combine: + x_old + vn[batch] + bias, store bf16, BN stats (from f32 r)
  float s0 = 0.f, s1 = 0.f, s2 = 0.f, s3 = 0.f;
  float q0 = 0.f, q1 = 0.f, q2 = 0.f, q3 = 0.f;
#pragma unroll
  for (int j = 0; j < 4; j++) {
    floatx4 vv = *(const floatx4*)&vn[bt[j] * H + c];
    float r0 = a0[j] + blo(xo[j].x) + vv.x + bi.x;
    float r1 = a1[j] + bhi(xo[j].x) + vv.y + bi.y;
    float r2 = a2[j] + blo(xo[j].y) + vv.z + bi.z;
    float r3 = a3[j] + bhi(xo[j].y) + vv.w + bi.w;
    if (act[j]) {
      uint2 rv;
      rv.x = (unsigned)f2b(r0) | ((unsigned)f2b(r1) << 16);
      rv.y = (unsigned)f2b(r2) | ((unsigned)f2b(r3) << 16);
      *(uint2*)&x[(long)nd[j] * H + c] = rv;
      s0 += r0; q0 += r0 * r0;
      s1 += r1; q1 += r1 * r1;
      s2 += r2; q2 += r2 * r2;
      s3 += r3; q3 += r3 * r3;
    }
  }
  // cross-half reduce, then per-block LDS reduce + one atomic per column
  s0 += __shfl_xor(s0, 32); s1 += __shfl_xor(s1, 32);
  s2 += __shfl_xor(s2, 32); s3 += __shfl_xor(s3, 32);
  q0 += __shfl_xor(q0, 32); q1 += __shfl_xor(q1, 32);
  q2 += __shfl_xor(q2, 32); q3 += __shfl_xor(q3, 32);
  if (hh == 0) {
    floatx4 sv4 = {s0, s1, s2, s3};
    floatx4 qv4 = {q0, q1, q2, q3};
    *(floatx4*)&sred[w * H + c] = sv4;
    *(floatx4*)&qred[w * H + c] = qv4;
  }
  __syncthreads();
  int t = threadIdx.x;
  if (t < H) {
    float s = sred[t] + sred[H + t] + sred[2 * H + t] + sred[3 * H + t];
    if (s != 0.f) atomicAdd(&stats[t], s);
  } else {
    int cc = t - H;
    float q = qred[cc] + qred[H + cc] + qred[2 * H + cc] + qred[3 * H + cc];
    if (q != 0.f) atomicAdd(&stats[H + cc], q);
  }
}

// ---------------- BN finalize (stats -> scale/shift) + pooled zeroing ----------------
__global__ __launch_bounds__(128) void bn_finalize_kernel(const float* __restrict__ stats, const float* __restrict__ g,
                                                          const float* __restrict__ b, float* __restrict__ scsh,
                                                          float invN, float* __restrict__ pooled, int GH) {
  int c = threadIdx.x;
  float m = stats[c] * invN;
  float v = stats[H + c] * invN - m * m;
  float sc = rsqrtf(v + 1e-5f) * g[c];
  scsh[c] = sc;
  scsh[H + c] = b[c] - m * sc;
  for (int i = c; i < GH; i += 128) pooled[i] = 0.f;
}

// ---------------- conv GEMM: bf16 x input, B staged once in LDS, 1 barrier ----------------
// Block 0 also zeroes 'stats' for the gather_agg that follows.
__global__ __launch_bounds__(256) void conv_gemm(const unsigned short* __restrict__ x, const unsigned short* __restrict__ BT,
                                                 const float* __restrict__ vn, const int* __restrict__ batch,
                                                 unsigned short* __restrict__ h16, float* __restrict__ stats, int M) {
  __shared__ unsigned short Bs[H * LDC];  // 34816 B
  int tid = threadIdx.x;
  if (blockIdx.x == 0) stats[tid] = 0.f;  // 2*H == 256 == blockDim
  int lane = tid & 63, w = tid >> 6;
  int row0 = blockIdx.x * 64;
  int mrow = lane & 15, quad = lane >> 4, cn = lane & 15;
  int arow = row0 + w * 16 + mrow;
  bool rin = arow < M;
  int b = rin ? batch[arow] : 0;

  // x loads first (long-latency), then weight staging, then vn (small, L2-hot)
  short8 xr[4];
#pragma unroll
  for (int k0 = 0; k0 < 4; k0++) {
    int kb = k0 * 32 + quad * 8;
    xr[k0] = rin ? *(const short8*)&x[(long)arow * H + kb] : (short8)0;
  }

#pragma unroll
  for (int j = 0; j < 8; j++) {
    int chunk = j * 256 + tid;
    int n = chunk >> 4, k8 = (chunk & 15) * 8;
    *(short8*)&Bs[n * LDC + k8] = *(const short8*)&BT[(long)n * H + k8];
  }

  short8 af[4];
#pragma unroll
  for (int k0 = 0; k0 < 4; k0++) {
    int kb = k0 * 32 + quad * 8;
    floatx4 a0, a1;
    unpack8(xr[k0], a0, a1);
    if (rin) {
      a0 = a0 + *(const floatx4*)&vn[b * H + kb];
      a1 = a1 + *(const floatx4*)&vn[b * H + kb + 4];
    }
    af[k0] = pack8(a0, a1);
  }
  __syncthreads();

  floatx4 aacc[8];
#pragma unroll
  for (int t = 0; t < 8; t++) {
    floatx4 a = (floatx4)0.f;
#pragma unroll
    for (int k0 = 0; k0 < 4; k0++) {
      int kb = k0 * 32 + quad * 8;
      short8 bf = *(const short8*)&Bs[(t * 16 + mrow) * LDC + kb];
      a = __builtin_amdgcn_mfma_f32_16x16x32_bf16(af[k0], bf, a, 0, 0, 0);
    }
    aacc[t] = a;
  }
  // i-outer / t-inner store order: per-row chunks issued consecutively -> line combining
#pragma unroll
  for (int i = 0; i < 4; i++) {
    int r = row0 + w * 16 + quad * 4 + i;
    if (r < M) {
#pragma unroll
      for (int t = 0; t < 8; t++) h16[(long)r * H + t * 16 + cn] = f2b(aacc[t][i]);
    }
  }
}

// ---------------- fused 2-layer FFN, small-LDS variant (pre-FFN: f32 in, bf16 out) ----------------
// Epilogue transposes through per-wave HsW so C stores are short8 (16B/lane).
template <int BNRES>
__global__ __launch_bounds__(256) void ffn_fused(const float* __restrict__ A,
                                                 const unsigned short* __restrict__ W1T, const float* __restrict__ b1,
                                                 const unsigned short* __restrict__ W2T, const float* __restrict__ b2,
                                                 const float* __restrict__ scsh,
                                                 unsigned short* __restrict__ C, int M) {
  __shared__ unsigned short smem[FFN_SMEM];  // 18432 shorts = 36864 B
  unsigned short* Bs1 = smem;                // phase 1: 256 rows x 64-k slice
  unsigned short* Bs2 = smem + 4 * 16 * LDHW;// phase 2: 128 rows x 64-k slice

  int tid = threadIdx.x;
  int lane = tid & 63, w = tid >> 6;
  unsigned short* HsW = smem + w * 16 * LDHW;// per-wave hidden half: 16 x LDHW
  int row0 = blockIdx.x * 64;
  int mrow = lane & 15, quad = lane >> 4, cn = lane & 15;
  int arow = row0 + w * 16 + mrow;
  bool rin = arow < M;

  short8 af[4];
#pragma unroll
  for (int k0 = 0; k0 < 4; k0++) {
    int kb = k0 * 32 + quad * 8;
    floatx4 a0 = (floatx4)0.f, a1 = (floatx4)0.f;
    if (rin) {
      a0 = *(const floatx4*)&A[(long)arow * H + kb];
      a1 = *(const floatx4*)&A[(long)arow * H + kb + 4];
      if (BNRES) {
        a0 = a0 * *(const floatx4*)&scsh[kb] + *(const floatx4*)&scsh[H + kb];
        a1 = a1 * *(const floatx4*)&scsh[kb + 4] + *(const floatx4*)&scsh[H + kb + 4];
      }
    }
    af[k0] = pack8(a0, a1);
  }

  floatx4 acc1[16];
#pragma unroll
  for (int t = 0; t < 16; t++) acc1[t] = (floatx4)0.f;

  for (int ks = 0; ks < 2; ks++) {
    if (ks > 0) __syncthreads();
#pragma unroll
    for (int j = 0; j < 8; j++) {
      int chunk = j * 256 + tid;
      int n = chunk >> 3, k8 = (chunk & 7) * 8;
      *(short8*)&Bs1[n * LDK + k8] = *(const short8*)&W1T[(long)n * H + ks * 64 + k8];
    }
    __syncthreads();
#pragma unroll
    for (int t = 0; t < 16; t++) {
      int kb = quad * 8;
      short8 bf0 = *(const short8*)&Bs1[(t * 16 + mrow) * LDK + kb];
      acc1[t] = __builtin_amdgcn_mfma_f32_16x16x32_bf16(af[ks * 2], bf0, acc1[t], 0, 0, 0);
      short8 bf1 = *(const short8*)&Bs1[(t * 16 + mrow) * LDK + 32 + kb];
      acc1[t] = __builtin_amdgcn_mfma_f32_16x16x32_bf16(af[ks * 2 + 1], bf1, acc1[t], 0, 0, 0);
    }
  }
  __syncthreads();  // all waves done reading Bs1 before HsW/Bs2 overwrite it

  // hidden -> A-fragments via per-wave LDS half-buffers (intra-wave, no barriers)
  short8 hf[8];
#pragma unroll
  for (int half = 0; half < 2; half++) {
#pragma unroll
    for (int t = 0; t < 8; t++) {
      int tt = half * 8 + t;
      int cg = tt * 16 + cn;
      int cl = t * 16 + cn;
      float bb = b1[cg];
#pragma unroll
      for (int i = 0; i < 4; i++) {
        int r = quad * 4 + i;
        HsW[r * LDHW + cl] = f2b(gelu_f(acc1[tt][i] + bb));
      }
    }
#pragma unroll
    for (int k0 = 0; k0 < 4; k0++)
      hf[half * 4 + k0] = *(const short8*)&HsW[mrow * LDHW + k0 * 32 + quad * 8];
  }

#pragma unroll
  for (int j = 0; j < 4; j++) {
    int chunk = j * 256 + tid;
    int n = chunk >> 3, k8 = (chunk & 7) * 8;
    *(short8*)&Bs2[n * LDK + k8] = *(const short8*)&W2T[(long)n * H2 + k8];
  }
  __syncthreads();

  floatx4 acc2[8];
#pragma unroll
  for (int t = 0; t < 8; t++) acc2[t] = (floatx4)0.f;

  for (int ks = 0; ks < 4; ks++) {
    if (ks > 0) {
      __syncthreads();
#pragma unroll
      for (int j = 0; j < 4; j++) {
        int chunk = j * 256 + tid;
        int n = chunk >> 3, k8 = (chunk & 7) * 8;
        *(short8*)&Bs2[n * LDK + k8] = *(const short8*)&W2T[(long)n * H2 + ks * 64 + k8];
      }
      __syncthreads();
    }
    int kk = ks * 2;
#pragma unroll
    for (int t = 0; t < 8; t++) {
      int kb0 = quad * 8;
      short8 bf0 = *(const short8*)&Bs2[(t * 16 + mrow) * LDK + kb0];
      acc2[t] = __builtin_amdgcn_mfma_f32_16x16x32_bf16(hf[kk], bf0, acc2[t], 0, 0, 0);
      short8 bf1 = *(const short8*)&Bs2[(t * 16 + mrow) * LDK + 32 + kb0];
      acc2[t] = __builtin_amdgcn_mfma_f32_16x16x32_bf16(hf[kk + 1], bf1, acc2[t], 0, 0, 0);
    }
  }

  // epilogue: transpose via HsW (per-wave, intra-wave ordering), wide short8 stores
#pragma unroll
  for (int t = 0; t < 8; t++) {
    float bb = b2[t * 16 + cn];
#pragma unroll
    for (int i = 0; i < 4; i++)
      HsW[(quad * 4 + i) * LDHW + t * 16 + cn] = f2b(gelu_f(acc2[t][i] + bb));
  }
#pragma unroll
  for (int k0 = 0; k0 < 4; k0++) {
    int CB = k0 * 32 + quad * 8;
    short8 gv = *(const short8*)&HsW[mrow * LDHW + CB];
    if (rin) {
      if (BNRES) {
        floatx4 g0v, g1v, r0, r1;
        unpack8(gv, g0v, g1v);
        short8 rx = *(const short8*)&C[(long)arow * H + CB];
        unpack8(rx, r0, r1);
        g0v = g0v + r0 * *(const floatx4*)&scsh[CB] + *(const floatx4*)&scsh[H + CB];
        g1v = g1v + r1 * *(const floatx4*)&scsh[CB + 4] + *(const floatx4*)&scsh[H + CB + 4];
        gv = pack8(g0v, g1v);
      }
      *(short8*)&C[(long)arow * H + CB] = gv;
    }
  }
}

// ---------------- persistent fused 2-layer FFN (in-loop: bf16 x in/out, weights LDS-resident) ----------------
// 256 blocks x 1024 threads (1 block/CU, 16 waves). Stage W1+W2 once, then per-wave
// 16-row tiles with zero barriers. A-loads go DIRECTLY into pack8 (no staging array).
// Epilogue: per 32-col chunk, acc2 -> scr (bf16) -> row-major short8; residual read
// and C store are 16B/lane (same shape as A-load); pooling via shfl row-reduce.
template <int BNRES, int POOL>
__global__ __launch_bounds__(1024) void ffn_persist(const unsigned short* __restrict__ A,
                                                    const unsigned short* __restrict__ W1T, const float* __restrict__ b1,
                                                    const unsigned short* __restrict__ W2T, const float* __restrict__ b2,
                                                    const float* __restrict__ scsh,
                                                    unsigned short* __restrict__ C, float* __restrict__ pooled,
                                                    const int* __restrict__ batch, int M) {
  __shared__ unsigned short lds[78848];  // 157696 B
  int tid = threadIdx.x;
#pragma unroll
  for (int j = 0; j < 4; j++) {
    int idx = j * 1024 + tid;
    int n = idx >> 4, k8 = (idx & 15) * 8;
    *(short8*)&lds[n * 136 + k8] = *(const short8*)&W1T[n * 128 + k8];
  }
#pragma unroll
  for (int j = 0; j < 4; j++) {
    int idx = j * 1024 + tid;
    int n = idx >> 5, k8 = (idx & 31) * 8;
    *(short8*)&lds[34816 + n * 264 + k8] = *(const short8*)&W2T[n * 256 + k8];
  }
  __syncthreads();

  int lane = tid & 63, w = tid >> 6;
  int mrow = lane & 15, quad = lane >> 4, cn = lane & 15;
  unsigned short* scr = &lds[68608 + w * 640];
  int TT = (M + 15) >> 4;
  int stride = (int)(gridDim.x << 4);

  for (int tile = blockIdx.x * 16 + w; tile < TT; tile += stride) {
    int row0 = tile << 4;
    int arow = row0 + mrow;
    bool rin = arow < M;

    short8 af[4];
#pragma unroll
    for (int k0 = 0; k0 < 4; k0++) {
      int kb = k0 * 32 + quad * 8;
      short8 s = rin ? *(const short8*)&A[(long)arow * H + kb] : (short8)0;
      floatx4 a0, a1;
      unpack8(s, a0, a1);
      if (BNRES) {
        a0 = a0 * *(const floatx4*)&scsh[kb] + *(const floatx4*)&scsh[H + kb];
        a1 = a1 * *(const floatx4*)&scsh[kb + 4] + *(const floatx4*)&scsh[H + kb + 4];
      }
      af[k0] = pack8(a0, a1);
    }

    floatx4 acc2[8];
#pragma unroll
    for (int t = 0; t < 8; t++) acc2[t] = (floatx4)0.f;

#pragma unroll
    for (int p = 0; p < 8; p++) {
      // phase 1: hidden tiles t = 2p, 2p+1 (32 hidden cols), K=128
#pragma unroll
      for (int u = 0; u < 2; u++) {
        int t = p * 2 + u;
        floatx4 a = (floatx4)0.f;
#pragma unroll
        for (int k = 0; k < 4; k++) {
          short8 bf = *(const short8*)&lds[(t * 16 + mrow) * 136 + k * 32 + quad * 8];
          a = __builtin_amdgcn_mfma_f32_16x16x32_bf16(af[k], bf, a, 0, 0, 0);
        }
        float bb = b1[t * 16 + cn];
#pragma unroll
        for (int i = 0; i < 4; i++)
          scr[(quad * 4 + i) * 40 + u * 16 + cn] = f2b(gelu_f(a[i] + bb));
      }
      // transpose readback: A-frag for hidden k-chunk p (row=mrow, k=quad*8..+7)
      short8 hf = *(const short8*)&scr[mrow * 40 + quad * 8];
      // phase 2: accumulate this 32-k chunk into all 8 output col-tiles
#pragma unroll
      for (int ct = 0; ct < 8; ct++) {
        short8 bf = *(const short8*)&lds[34816 + (ct * 16 + mrow) * 264 + p * 32 + quad * 8];
        acc2[ct] = __builtin_amdgcn_mfma_f32_16x16x32_bf16(hf, bf, acc2[ct], 0, 0, 0);
      }
    }

    // epilogue: 4 chunks of 32 cols, transposed through scr; wide residual+store
    int g0 = 0; bool same = true;
    if (POOL) {
      int rl = row0 + 15; if (rl >= M) rl = M - 1;
      g0 = batch[row0];
      same = (batch[rl] == g0);
    }
#pragma unroll
    for (int cc = 0; cc < 4; cc++) {
      // stage gelu(acc2 + b2) for col-tiles t = 2cc, 2cc+1 into scr[16][40]
#pragma unroll
      for (int u = 0; u < 2; u++) {
        int t = cc * 2 + u;
        float bb = b2[t * 16 + cn];
#pragma unroll
        for (int i = 0; i < 4; i++)
          scr[(quad * 4 + i) * 40 + u * 16 + cn] = f2b(gelu_f(acc2[t][i] + bb));
      }
      // row-major readback: row mrow, cols CB..CB+8
      int CB = cc * 32 + quad * 8;
      short8 gv = *(const short8*)&scr[mrow * 40 + quad * 8];
      floatx4 v0, v1;
      unpack8(gv, v0, v1);
      if (BNRES) {
        short8 rx = rin ? *(const short8*)&C[(long)arow * H + CB] : (short8)0;
        floatx4 r0, r1;
        unpack8(rx, r0, r1);
        v0 = v0 + r0 * *(const floatx4*)&scsh[CB] + *(const floatx4*)&scsh[H + CB];
        v1 = v1 + r1 * *(const floatx4*)&scsh[CB + 4] + *(const floatx4*)&scsh[H + CB + 4];
      }
      if (!rin) { v0 = (floatx4)0.f; v1 = (floatx4)0.f; }
      if (rin) *(short8*)&C[(long)arow * H + CB] = pack8(v0, v1);
      if (POOL) {
        if (same) {
          // column sums over the 16 rows (lanes differing in mrow)
#pragma unroll
          for (int d = 1; d < 16; d <<= 1) {
#pragma unroll
            for (int q = 0; q < 4; q++) {
              v0[q] += __shfl_xor(v0[q], d);
              v1[q] += __shfl_xor(v1[q], d);
            }
          }
          if (mrow == 0) {
#pragma unroll
            for (int q = 0; q < 4; q++) {
              atomicAdd(&pooled[g0 * H + CB + q], v0[q]);
              atomicAdd(&pooled[g0 * H + CB + 4 + q], v1[q]);
            }
          }
        } else if (rin) {
          int bg = batch[arow];
#pragma unroll
          for (int q = 0; q < 4; q++) {
            atomicAdd(&pooled[bg * H + CB + q], v0[q]);
            atomicAdd(&pooled[bg * H + CB + 4 + q], v1[q]);
          }
        }
      }
    }
  }
}

// ---------------- parallel 64-row MLP stages (vn / post) ----------------
template <int BN, int UVN>
__global__ __launch_bounds__(256) void mlp64_l1(const float* __restrict__ vn, const float* __restrict__ pooled,
                                                const float* __restrict__ counts,
                                                const float* __restrict__ W1, const float* __restrict__ b1,
                                                const float* __restrict__ g1, const float* __restrict__ be1,
                                                float* __restrict__ h1) {
  __shared__ float u[64 * H];
  __shared__ float red[8 * 64];
  int t = threadIdx.x;
  for (int idx = t; idx < 64 * H; idx += 256) {
    float v = pooled[idx];
    if (UVN) v = vn[idx] + v / fmaxf(counts[idx >> 7], 1.0f);
    u[idx] = v;
  }
  __syncthreads();
  int tc = t & 63, tg = t >> 6;
  int c = blockIdx.x * 64 + tc;
  float acc[16];
  float bj = b1[c];
#pragma unroll
  for (int g = 0; g < 16; g++) acc[g] = bj;
  for (int k0 = 0; k0 < H; k0 += 4) {
    float w0 = W1[(k0 + 0) * H2 + c];
    float w1 = W1[(k0 + 1) * H2 + c];
    float w2 = W1[(k0 + 2) * H2 + c];
    float w3 = W1[(k0 + 3) * H2 + c];
#pragma unroll
    for (int g = 0; g < 16; g++) {
      float4 v = *(const float4*)&u[(tg * 16 + g) * H + k0];
      acc[g] += v.x * w0 + v.y * w1 + v.z * w2 + v.w * w3;
    }
  }
  float sc = 1.f, sh = 0.f;
  if (BN) {
    float s = 0.f, s2 = 0.f;
#pragma unroll
    for (int g = 0; g < 16; g++) { s += acc[g]; s2 += acc[g] * acc[g]; }
    red[tg * 64 + tc] = s;
    red[256 + tg * 64 + tc] = s2;
    __syncthreads();
    float st = red[tc] + red[64 + tc] + red[128 + tc] + red[192 + tc];
    float st2 = red[256 + tc] + red[320 + tc] + red[384 + tc] + red[448 + tc];
    float m = st * (1.f / 64.f);
    float var = st2 * (1.f / 64.f) - m * m;
    sc = rsqrtf(var + 1e-5f) * g1[c];
    sh = be1[c] - m * sc;
  }
#pragma unroll
  for (int g = 0; g < 16; g++) h1[(tg * 16 + g) * H2 + c] = gelu_f(acc[g] * sc + sh);
}

template <int BN>
__global__ __launch_bounds__(256) void mlp64_l2(const float* __restrict__ h1,
                                                const float* __restrict__ W2, const float* __restrict__ b2,
                                                const float* __restrict__ g2, const float* __restrict__ be2,
                                                float* __restrict__ outp) {
  __shared__ float red[8 * 64];
  int t = threadIdx.x;
  int tc = t & 63, tg = t >> 6;
  int c = blockIdx.x * 64 + tc;
  float acc[16];
  float bj = b2[c];
#pragma unroll
  for (int g = 0; g < 16; g++) acc[g] = bj;
  for (int k0 = 0; k0 < H2; k0 += 4) {
    float w0 = W2[(k0 + 0) * H + c];
    float w1 = W2[(k0 + 1) * H + c];
    float w2 = W2[(k0 + 2) * H + c];
    float w3 = W2[(k0 + 3) * H + c];
#pragma unroll
    for (int g = 0; g < 16; g++) {
      float4 v = *(const float4*)&h1[(tg * 16 + g) * H2 + k0];
      acc[g] += v.x * w0 + v.y * w1 + v.z * w2 + v.w * w3;
    }
  }
  float sc = 1.f, sh = 0.f;
  if (BN) {
    float s = 0.f, s2 = 0.f;
#pragma unroll
    for (int g = 0; g < 16; g++) { s += acc[g]; s2 += acc[g] * acc[g]; }
    red[tg * 64 + tc] = s;
    red[256 + tg * 64 + tc] = s2;
    __syncthreads();
    float st = red[tc] + red[64 + tc] + red[128 + tc] + red[192 + tc];
    float st2 = red[256 + tc] + red[320 + tc] + red[384 + tc] + red[448 + tc];
    float m = st * (1.f / 64.f);
    float var = st2 * (1.f / 64.f) - m * m;
    sc = rsqrtf(var + 1e-5f) * g2[c];
    sh = be2[c] - m * sc;
  }
#pragma unroll
  for (int g = 0; g < 16; g++) outp[(tg * 16 + g) * H + c] = gelu_f(acc[g] * sc + sh);
}

// ---------------- host launch ----------------

extern "C" void kernel_launch(void* const* d_in, const int* in_sizes, int n_in,
                              void* d_out, int out_size, void* d_ws, size_t ws_size,
                              hipStream_t stream) {
  const float* x_in   = (const float*)d_in[0];
  const int*   edge   = (const int*)d_in[1];
  const int*   batch  = (const int*)d_in[2];
  const float* pre_W1 = (const float*)d_in[3];
  const float* pre_b1 = (const float*)d_in[4];
  const float* pre_W2 = (const float*)d_in[5];
  const float* pre_b2 = (const float*)d_in[6];
  const float* conv_W = (const float*)d_in[7];
  const float* conv_b = (const float*)d_in[8];
  const float* bn_g   = (const float*)d_in[9];
  const float* bn_b   = (const float*)d_in[10];
  const float* ffn_W1 = (const float*)d_in[11];
  const float* ffn_b1 = (const float*)d_in[12];
  const float* ffn_W2 = (const float*)d_in[13];
  const float* ffn_b2 = (const float*)d_in[14];
  const float* vn_W1  = (const float*)d_in[15];
  const float* vn_b1  = (const float*)d_in[16];
  const float* vn_g1  = (const float*)d_in[17];
  const float* vn_be1 = (const float*)d_in[18];
  const float* vn_W2  = (const float*)d_in[19];
  const float* vn_b2  = (const float*)d_in[20];
  const float* vn_g2  = (const float*)d_in[21];
  const float* vn_be2 = (const float*)d_in[22];
  const float* vn_emb = (const float*)d_in[23];
  const float* post_W1= (const float*)d_in[24];
  const float* post_b1= (const float*)d_in[25];
  const float* post_W2= (const float*)d_in[26];
  const float* post_b2= (const float*)d_in[27];
  float* out = (float*)d_out;

  const int N    = in_sizes[2];
  const int E    = in_sizes[1] / 2;
  const int G    = out_size / H;
  const int HOPS = in_sizes[7] / (H * H);
  const int NH   = N * H;

  // workspace layout
  float* w = (float*)d_ws;
  unsigned short* buf_xh = (unsigned short*)w;  w += NH / 2;  // bf16 x carrier
  float* buf_t  = w;  w += N * H2;
  unsigned short* buf_h16 = (unsigned short*)buf_t;
  float* dinv   = w;  w += N;
  float* counts = w;  w += G;
  float* stats  = w;  w += 2 * H;
  float* scsh   = w;  w += 2 * H;
  float* pooled = w;  w += G * H;
  float* vn     = w;  w += G * H;
  float* mlp_h1 = w;  w += G * H2;
  float* csr_norm = w; w += E;
  int* iw = (int*)w;
  int* cnt      = iw;  iw += N;
  int* row_ptr  = iw;  iw += N + 1;
  int* cursor   = iw;  iw += N;
  int* csr_src  = iw;  iw += E;
  int* blockSum = iw;  iw += 1024;
  int* blockOff = iw;  iw += 1024;
  unsigned short* wt = (unsigned short*)iw;
  unsigned short* preW1T = wt;  wt += H * H2;
  unsigned short* preW2T = wt;  wt += H2 * H;
  unsigned short* convT  = wt;  wt += HOPS * H * H;
  unsigned short* ffn1T  = wt;  wt += HOPS * H * H2;
  unsigned short* ffn2T  = wt;  wt += HOPS * H2 * H;

  const int* src = edge;
  const int* dst = edge + E;

  int gE  = (E + 255) / 256;
  int gM  = (N + 63) / 64;
  int nb  = (N + 1023) / 1024;
  float invN = 1.0f / (float)N;

  // weight transposes
  transpose_w<<<(H * H2 + 255) / 256, 256, 0, stream>>>(pre_W1, preW1T, H, H2, H * H2);
  transpose_w<<<(H2 * H + 255) / 256, 256, 0, stream>>>(pre_W2, preW2T, H2, H, H2 * H);
  transpose_w<<<(HOPS * H * H + 255) / 256, 256, 0, stream>>>(conv_W, convT, H, H, HOPS * H * H);
  transpose_w<<<(HOPS * H * H2 + 255) / 256, 256, 0, stream>>>(ffn_W1, ffn1T, H, H2, HOPS * H * H2);
  transpose_w<<<(HOPS * H2 * H + 255) / 256, 256, 0, stream>>>(ffn_W2, ffn2T, H2, H, HOPS * H2 * H);

  // CSR build + dinv
  hipMemsetAsync(cnt, 0, N * sizeof(int), stream);
  hist_kernel<<<gE, 256, 0, stream>>>(cnt, dst, E);
  scan_a<<<nb, 256, 0, stream>>>(cnt, row_ptr, blockSum, dinv, N);
  scan_b<<<1, 1024, 0, stream>>>(blockSum, blockOff, nb, row_ptr, N, E);
  scan_c<<<nb, 256, 0, stream>>>(row_ptr, blockOff, N);
  hipMemsetAsync(cursor, 0, N * sizeof(int), stream);
  build_csr_kernel<<<gE, 256, 0, stream>>>(src, dst, row_ptr, cursor, dinv, csr_src, csr_norm, E);

  // graph counts, vn init
  hipMemsetAsync(counts, 0, G * sizeof(float), stream);
  count_kernel<<<(N + 256 * 16 - 1) / (256 * 16), 256, 0, stream>>>(counts, batch, N, G);
  vn_init_kernel<<<(G * H + 255) / 256, 256, 0, stream>>>(vn, vn_emb, G * H);

  // pre-FFNN: cold f32 x_in -> bf16 buf_xh (many-block small-LDS variant)
  ffn_fused<0><<<gM, 256, 0, stream>>>(x_in, preW1T, pre_b1, preW2T, pre_b2, nullptr, buf_xh, N);

  for (int i = 0; i < HOPS; i++) {
    // GCN: h16 = bf16( (x + vn[batch]) @ W ); block 0 zeroes stats for gather
    conv_gemm<<<gM, 256, 0, stream>>>(buf_xh, convT + i * H * H, vn, batch, buf_h16, stats, N);
    // x = x + vn[batch] + bias + selfloop + gathered edges; BN stats fused (f32)
    gather_agg<<<(N + 31) / 32, 256, 0, stream>>>(buf_h16, csr_src, csr_norm, row_ptr, dinv, vn, batch,
                                                  conv_b + i * H, buf_xh, stats, N);
    // stats -> scale/shift; also zeroes pooled for the ffn_persist POOL atomics
    bn_finalize_kernel<<<1, 128, 0, stream>>>(stats, bn_g + i * H, bn_b + i * H, scsh, invN, pooled, G * H);
    // fused FFN: x = gelu(gelu(bn(x)@W1+b1)@W2+b2) + bn(x); pooling fused into epilogue
    ffn_persist<1, 1><<<256, 1024, 0, stream>>>(buf_xh, ffn1T + i * H * H2, ffn_b1 + i * H2,
                                                ffn2T + i * H2 * H, ffn_b2 + i * H, scsh,
                                                buf_xh, pooled, batch, N);
    // virtual node update
    if (i < HOPS - 1) {
      mlp64_l1<1, 1><<<H2 / 64, 256, 0, stream>>>(vn, pooled, counts,
                                                  vn_W1 + i * H * H2, vn_b1 + i * H2, vn_g1 + i * H2, vn_be1 + i * H2,
                                                  mlp_h1);
      mlp64_l2<1><<<H / 64, 256, 0, stream>>>(mlp_h1, vn_W2 + i * H2 * H, vn_b2 + i * H, vn_g2 + i * H, vn_be2 + i * H, vn);
    }
  }

  // final global_add_pool came fused from the last ffn_persist; post-FFNN
  mlp64_l1<0, 0><<<H2 / 64, 256, 0, stream>>>(nullptr, pooled, nullptr, post_W1, post_b1, nullptr, nullptr, mlp_h1);
  mlp64_l2<0><<<H / 64, 256, 0, stream>>>(mlp_h1, post_W2, post_b2, nullptr, nullptr, out);
}

// Round 13
// 1727.735 us; speedup vs baseline: 1.1426x; 1.1426x over previous
//
#include <hip/hip_runtime.h>
#include <math.h>

#define H 128
#define H2 256
#define LDC 136   // LDS row stride (bf16) for conv weight rows (128 k)
#define LDK 72    // LDS row stride (bf16) for 64-wide k rows (ffn_fused)
#define LDHW 136  // LDS row stride (bf16) for per-wave hidden half (ffn_fused)
#define FFN_SMEM (H2 * LDK)  // 18432 shorts = 36864 B -> 4 blocks/CU
// persistent FFN LDS layout (shorts):
//   W1s: [256][136]  = 34816          (rows: hidden col n, 128 k + pad8)
//   W2s: [128][264]  = 33792 @34816   (rows: out col c, 256 k + pad8)
//   scr: 16 waves x [16][40] = 10240 @68608  (per-wave hidden transpose)
// total 78848 shorts = 157696 B  (<= 160 KiB/CU, 1 block/CU, 16 waves)
// REG DISCIPLINE (round-3/6 spill lesson): at 16 waves/CU the budget is 128
// unified VGPR+AGPR per wave. A-loads must go DIRECTLY into pack8 (no staging
// array, no cross-iteration liveness) — staging-array variants spill.
// TILE MAPPING (round-8 lesson): grid-stride (blockIdx*16+w, +=4096) keeps the
// instantaneous working set contiguous -> even HBM channel interleave.
// X-PRECISION (rounds 10-12, REFUTED): bf16 x sped conv/gather but the FFN's
// in-place residual+write path showed 6-7x write amplification under three
// different store shapes (2B t-outer, 2B i-outer, 16B/lane transposed) —
// mechanism not understood; f32 carrier is strictly faster end-to-end.

typedef __attribute__((ext_vector_type(8))) short short8;
typedef __attribute__((ext_vector_type(4))) float floatx4;

// fast GELU: x * sigmoid(1.5957691*x*(1+0.044715*x^2)); max |dev| from exact erf-GELU ~1e-3
__device__ __forceinline__ float gelu_f(float x) {
  float t = 1.59576912161f * x * fmaf(0.044715f, x * x, 1.0f);
  return x / (1.0f + __expf(-t));
}

__device__ __forceinline__ unsigned short f2b(float f) {
  union { float f; unsigned u; } c; c.f = f;
  unsigned r = c.u + 0x7fffu + ((c.u >> 16) & 1u);
  return (unsigned short)(r >> 16);
}

__device__ __forceinline__ float b2f(unsigned short u) {
  union { unsigned u; float f; } c; c.u = ((unsigned)u) << 16; return c.f;
}

__device__ __forceinline__ float blo(unsigned u) { return __uint_as_float(u << 16); }
__device__ __forceinline__ float bhi(unsigned u) { return __uint_as_float(u & 0xffff0000u); }

__device__ __forceinline__ short8 pack8(floatx4 a, floatx4 b) {
  union { short8 v; unsigned short s[8]; } u;
  u.s[0] = f2b(a.x); u.s[1] = f2b(a.y); u.s[2] = f2b(a.z); u.s[3] = f2b(a.w);
  u.s[4] = f2b(b.x); u.s[5] = f2b(b.y); u.s[6] = f2b(b.z); u.s[7] = f2b(b.w);
  return u.v;
}

// ---------------- weight transpose+convert: W[b][K][N] fp32 -> WT[b][N][K] bf16 ----------------
__global__ __launch_bounds__(256) void transpose_w(const float* __restrict__ W, unsigned short* __restrict__ WT,
                                                   int K, int Ncol, int total) {
  int i = blockIdx.x * 256 + threadIdx.x;
  if (i >= total) return;
  int kn = K * Ncol;
  int b = i / kn, r = i - b * kn;
  int k = r / Ncol, n = r - k * Ncol;
  WT[b * kn + n * K + k] = f2b(W[i]);
}

// ---------------- CSR build ----------------

__global__ __launch_bounds__(256) void hist_kernel(int* __restrict__ cnt, const int* __restrict__ dst, int E) {
  int i = blockIdx.x * 256 + threadIdx.x;
  if (i < E) atomicAdd(&cnt[dst[i]], 1);
}

__global__ __launch_bounds__(256) void scan_a(const int* __restrict__ cnt, int* __restrict__ row_ptr,
                                              int* __restrict__ blockSum, float* __restrict__ dinv, int N) {
  __shared__ int ls[256];
  int t = threadIdx.x;
  int idx = blockIdx.x * 1024 + t * 4;
  int4 v = make_int4(0, 0, 0, 0);
  if (idx + 3 < N) v = *(const int4*)&cnt[idx];
  else {
    if (idx + 0 < N) v.x = cnt[idx + 0];
    if (idx + 1 < N) v.y = cnt[idx + 1];
    if (idx + 2 < N) v.z = cnt[idx + 2];
    if (idx + 3 < N) v.w = cnt[idx + 3];
  }
  if (idx + 0 < N) dinv[idx + 0] = rsqrtf((float)v.x + 1.0f);
  if (idx + 1 < N) dinv[idx + 1] = rsqrtf((float)v.y + 1.0f);
  if (idx + 2 < N) dinv[idx + 2] = rsqrtf((float)v.z + 1.0f);
  if (idx + 3 < N) dinv[idx + 3] = rsqrtf((float)v.w + 1.0f);
  int s = v.x + v.y + v.z + v.w;
  ls[t] = s;
  __syncthreads();
  for (int off = 1; off < 256; off <<= 1) {
    int a = (t >= off) ? ls[t - off] : 0;
    __syncthreads();
    ls[t] += a;
    __syncthreads();
  }
  int p = ls[t] - s;
  if (t == 255) blockSum[blockIdx.x] = ls[255];
  if (idx + 0 < N) row_ptr[idx + 0] = p;  p += v.x;
  if (idx + 1 < N) row_ptr[idx + 1] = p;  p += v.y;
  if (idx + 2 < N) row_ptr[idx + 2] = p;  p += v.z;
  if (idx + 3 < N) row_ptr[idx + 3] = p;
}

__global__ __launch_bounds__(1024) void scan_b(const int* __restrict__ blockSum, int* __restrict__ blockOff,
                                               int nb, int* __restrict__ row_ptr, int N, int E) {
  __shared__ int ls[1024];
  int t = threadIdx.x;
  int s = (t < nb) ? blockSum[t] : 0;
  ls[t] = s;
  __syncthreads();
  for (int off = 1; off < 1024; off <<= 1) {
    int a = (t >= off) ? ls[t - off] : 0;
    __syncthreads();
    ls[t] += a;
    __syncthreads();
  }
  if (t < nb) blockOff[t] = ls[t] - s;
  if (t == 0) row_ptr[N] = E;
}

__global__ __launch_bounds__(256) void scan_c(int* __restrict__ row_ptr, const int* __restrict__ blockOff, int N) {
  int t = threadIdx.x;
  int idx = blockIdx.x * 1024 + t * 4;
  int off = blockOff[blockIdx.x];
  if (off == 0) return;
  if (idx + 3 < N) {
    int4 v = *(const int4*)&row_ptr[idx];
    v.x += off; v.y += off; v.z += off; v.w += off;
    *(int4*)&row_ptr[idx] = v;
  } else {
    if (idx + 0 < N) row_ptr[idx + 0] += off;
    if (idx + 1 < N) row_ptr[idx + 1] += off;
    if (idx + 2 < N) row_ptr[idx + 2] += off;
    if (idx + 3 < N) row_ptr[idx + 3] += off;
  }
}

__global__ __launch_bounds__(256) void build_csr_kernel(const int* __restrict__ src, const int* __restrict__ dst,
                                                        const int* __restrict__ row_ptr, int* __restrict__ cursor,
                                                        const float* __restrict__ dinv,
                                                        int* __restrict__ csr_src, float* __restrict__ csr_norm,
                                                        int E) {
  int i = blockIdx.x * 256 + threadIdx.x;
  if (i < E) {
    int s = src[i], d = dst[i];
    int pos = row_ptr[d] + atomicAdd(&cursor[d], 1);
    csr_src[pos] = s;
    csr_norm[pos] = dinv[s] * dinv[d];
  }
}

// ---------------- small setup kernels ----------------

__global__ __launch_bounds__(256) void count_kernel(float* counts, const int* __restrict__ batch, int N, int G) {
  __shared__ float hist[256];
  int t = threadIdx.x;
  if (t < G) hist[t] = 0.f;
  __syncthreads();
  int i0 = (blockIdx.x * 256 + t) * 16;
  int cur = -1; float run = 0.f;
  for (int j = 0; j < 16; j++) {
    int i = i0 + j;
    if (i < N) {
      int b = batch[i];
      if (b == cur) run += 1.f;
      else { if (cur >= 0) atomicAdd(&hist[cur], run); cur = b; run = 1.f; }
    }
  }
  if (cur >= 0) atomicAdd(&hist[cur], run);
  __syncthreads();
  if (t < G && hist[t] != 0.f) atomicAdd(&counts[t], hist[t]);
}

__global__ __launch_bounds__(256) void vn_init_kernel(float* vn, const float* __restrict__ emb, int n) {
  int i = blockIdx.x * 256 + threadIdx.x;
  if (i < n) vn[i] = emb[i & (H - 1)];
}

// ---------------- fused gather aggregation (bf16 h) + BN stats ----------------
// 2 nodes per wave-instruction (half-wave per node, 4 ch/lane). 8 nodes/wave as 4 pairs.
__global__ __launch_bounds__(256) void gather_agg(const unsigned short* __restrict__ h, const int* __restrict__ csr_src,
                                                  const float* __restrict__ csr_norm, const int* __restrict__ row_ptr,
                                                  const float* __restrict__ dinv, const float* __restrict__ vn,
                                                  const int* __restrict__ batch, const float* __restrict__ bias,
                                                  float* __restrict__ x, float* __restrict__ stats, int N) {
  __shared__ float sred[4 * H];
  __shared__ float qred[4 * H];
  int w = threadIdx.x >> 6, lane = threadIdx.x & 63;
  int hh = lane >> 5;          // which node of the pair
  int li = lane & 31;
  int c = li * 4;              // 4 channels per lane
  floatx4 bi = *(const floatx4*)&bias[c];
  int base = blockIdx.x * 32 + w * 8;

  int nd[4]; bool act[4];
#pragma unroll
  for (int j = 0; j < 4; j++) {
    int n0 = base + 2 * j + hh;
    act[j] = n0 < N;
    nd[j] = act[j] ? n0 : (N - 1);
  }
  int beg[4], end[4], bt[4];
  float dd[4];
#pragma unroll
  for (int j = 0; j < 4; j++) { beg[j] = row_ptr[nd[j]]; end[j] = row_ptr[nd[j] + 1]; }
#pragma unroll
  for (int j = 0; j < 4; j++) { bt[j] = batch[nd[j]]; float di = dinv[nd[j]]; dd[j] = di * di; }
  floatx4 xo[4]; uint2 hs[4];
#pragma unroll
  for (int j = 0; j < 4; j++) {
    xo[j] = *(const floatx4*)&x[(long)nd[j] * H + c];
    hs[j] = *(const uint2*)&h[(long)nd[j] * H + c];
  }
  float a0[4], a1[4], a2[4], a3[4];
#pragma unroll
  for (int j = 0; j < 4; j++) {
    a0[j] = blo(hs[j].x) * dd[j];
    a1[j] = bhi(hs[j].x) * dd[j];
    a2[j] = blo(hs[j].y) * dd[j];
    a3[j] = bhi(hs[j].y) * dd[j];
  }

#define GROUP_CSR(j, eb, sv, nv)                      \
  int sv; float nv;                                   \
  {                                                   \
    int idx_ = beg[j] + (eb) + li;                    \
    bool vld_ = (li < 8) && (idx_ < end[j]);          \
    int sidx_ = vld_ ? idx_ : 0;                      \
    sv = csr_src[sidx_];                              \
    nv = vld_ ? csr_norm[sidx_] : 0.f;                \
  }

#define GROUP_GACC(j, sv, nv)                         \
  {                                                   \
    uint2 u_[8]; float wg_[8];                        \
    _Pragma("unroll")                                 \
    for (int ii = 0; ii < 8; ii++) {                  \
      wg_[ii] = __shfl(nv, hh * 32 + ii);             \
      int si_ = __shfl(sv, hh * 32 + ii);             \
      u_[ii] = *(const uint2*)&h[(long)si_ * H + c];  \
    }                                                 \
    _Pragma("unroll")                                 \
    for (int ii = 0; ii < 8; ii++) {                  \
      a0[j] += blo(u_[ii].x) * wg_[ii];               \
      a1[j] += bhi(u_[ii].x) * wg_[ii];               \
      a2[j] += blo(u_[ii].y) * wg_[ii];               \
      a3[j] += bhi(u_[ii].y) * wg_[ii];               \
    }                                                 \
  }

  // first edge-group of all 4 pairs: csr loads all issued first
  {
    GROUP_CSR(0, 0, sv0, nv0)
    GROUP_CSR(1, 0, sv1, nv1)
    GROUP_CSR(2, 0, sv2, nv2)
    GROUP_CSR(3, 0, sv3, nv3)
    GROUP_GACC(0, sv0, nv0)
    GROUP_GACC(1, sv1, nv1)
    GROUP_GACC(2, sv2, nv2)
    GROUP_GACC(3, sv3, nv3)
  }

  // tails (deg > 8): interleave needed groups across pairs per round
  int dmx[4];
#pragma unroll
  for (int j = 0; j < 4; j++) {
    int d = end[j] - beg[j];
    int dx = __shfl_xor(d, 32);
    dmx[j] = d > dx ? d : dx;      // wave-uniform per pair
  }
  int dall = dmx[0];
  if (dmx[1] > dall) dall = dmx[1];
  if (dmx[2] > dall) dall = dmx[2];
  if (dmx[3] > dall) dall = dmx[3];
  for (int eb = 8; eb < dall; eb += 8) {
#pragma unroll
    for (int j = 0; j < 4; j++) {
      if (eb < dmx[j]) {
        GROUP_CSR(j, eb, svt, nvt)
        GROUP_GACC(j, svt, nvt)
      }
    }
  }
#undef GROUP_CSR
#undef GROUP_GACC

  // combine: + x_old + vn[batch] + bias, store, BN stats
  float s0 = 0.f, s1 = 0.f, s2 = 0.f, s3 = 0.f;
  float q0 = 0.f, q1 = 0.f, q2 = 0.f, q3 = 0.f;
#pragma unroll
  for (int j = 0; j < 4; j++) {
    floatx4 vv = *(const floatx4*)&vn[bt[j] * H + c];
    float r0 = a0[j] + xo[j].x + vv.x + bi.x;
    float r1 = a1[j] + xo[j].y + vv.y + bi.y;
    float r2 = a2[j] + xo[j].z + vv.z + bi.z;
    float r3 = a3[j] + xo[j].w + vv.w + bi.w;
    if (act[j]) {
      floatx4 rv = {r0, r1, r2, r3};
      *(floatx4*)&x[(long)nd[j] * H + c] = rv;
      s0 += r0; q0 += r0 * r0;
      s1 += r1; q1 += r1 * r1;
      s2 += r2; q2 += r2 * r2;
      s3 += r3; q3 += r3 * r3;
    }
  }
  // cross-half reduce, then per-block LDS reduce + one atomic per column
  s0 += __shfl_xor(s0, 32); s1 += __shfl_xor(s1, 32);
  s2 += __shfl_xor(s2, 32); s3 += __shfl_xor(s3, 32);
  q0 += __shfl_xor(q0, 32); q1 += __shfl_xor(q1, 32);
  q2 += __shfl_xor(q2, 32); q3 += __shfl_xor(q3, 32);
  if (hh == 0) {
    floatx4 sv4 = {s0, s1, s2, s3};
    floatx4 qv4 = {q0, q1, q2, q3};
    *(floatx4*)&sred[w * H + c] = sv4;
    *(floatx4*)&qred[w * H + c] = qv4;
  }
  __syncthreads();
  int t = threadIdx.x;
  if (t < H) {
    float s = sred[t] + sred[H + t] + sred[2 * H + t] + sred[3 * H + t];
    if (s != 0.f) atomicAdd(&stats[t], s);
  } else {
    int cc = t - H;
    float q = qred[cc] + qred[H + cc] + qred[2 * H + cc] + qred[3 * H + cc];
    if (q != 0.f) atomicAdd(&stats[H + cc], q);
  }
}

// ---------------- BN finalize (stats -> scale/shift) + pooled zeroing ----------------
// Also zeroes 'pooled' for the ffn_persist POOL atomics that follow (kernel-boundary
// ordering guarantees completion before ffn_persist starts) — saves a memset dispatch.
__global__ __launch_bounds__(128) void bn_finalize_kernel(const float* __restrict__ stats, const float* __restrict__ g,
                                                          const float* __restrict__ b, float* __restrict__ scsh,
                                                          float invN, float* __restrict__ pooled, int GH) {
  int c = threadIdx.x;
  float m = stats[c] * invN;
  float v = stats[H + c] * invN - m * m;
  float sc = rsqrtf(v + 1e-5f) * g[c];
  scsh[c] = sc;
  scsh[H + c] = b[c] - m * sc;
  for (int i = c; i < GH; i += 128) pooled[i] = 0.f;
}

// ---------------- conv GEMM: B staged once in LDS, A loads hoisted, 1 barrier ----------------
// Block 0 also zeroes 'stats' for the gather_agg that follows (saves a memset dispatch).
__global__ __launch_bounds__(256) void conv_gemm(const float* __restrict__ x, const unsigned short* __restrict__ BT,
                                                 const float* __restrict__ vn, const int* __restrict__ batch,
                                                 unsigned short* __restrict__ h16, float* __restrict__ stats, int M) {
  __shared__ unsigned short Bs[H * LDC];  // 34816 B
  int tid = threadIdx.x;
  if (blockIdx.x == 0) stats[tid] = 0.f;  // 2*H == 256 == blockDim
  int lane = tid & 63, w = tid >> 6;
  int row0 = blockIdx.x * 64;
  int mrow = lane & 15, quad = lane >> 4, cn = lane & 15;
  int arow = row0 + w * 16 + mrow;
  bool rin = arow < M;
  int b = rin ? batch[arow] : 0;

  // x loads first (long-latency), then weight staging, then vn (small, L2-hot)
  floatx4 xr[8];
#pragma unroll
  for (int k0 = 0; k0 < 4; k0++) {
    int kb = k0 * 32 + quad * 8;
    xr[2 * k0]     = rin ? *(const floatx4*)&x[(long)arow * H + kb]     : (floatx4)0.f;
    xr[2 * k0 + 1] = rin ? *(const floatx4*)&x[(long)arow * H + kb + 4] : (floatx4)0.f;
  }

#pragma unroll
  for (int j = 0; j < 8; j++) {
    int chunk = j * 256 + tid;
    int n = chunk >> 4, k8 = (chunk & 15) * 8;
    *(short8*)&Bs[n * LDC + k8] = *(const short8*)&BT[(long)n * H + k8];
  }

  short8 af[4];
#pragma unroll
  for (int k0 = 0; k0 < 4; k0++) {
    int kb = k0 * 32 + quad * 8;
    floatx4 a0 = xr[2 * k0], a1 = xr[2 * k0 + 1];
    if (rin) {
      a0 = a0 + *(const floatx4*)&vn[b * H + kb];
      a1 = a1 + *(const floatx4*)&vn[b * H + kb + 4];
    }
    af[k0] = pack8(a0, a1);
  }
  __syncthreads();

  floatx4 aacc[8];
#pragma unroll
  for (int t = 0; t < 8; t++) {
    floatx4 a = (floatx4)0.f;
#pragma unroll
    for (int k0 = 0; k0 < 4; k0++) {
      int kb = k0 * 32 + quad * 8;
      short8 bf = *(const short8*)&Bs[(t * 16 + mrow) * LDC + kb];
      a = __builtin_amdgcn_mfma_f32_16x16x32_bf16(af[k0], bf, a, 0, 0, 0);
    }
    aacc[t] = a;
  }
  // i-outer / t-inner store order: per-row chunks issued consecutively -> line combining
#pragma unroll
  for (int i = 0; i < 4; i++) {
    int r = row0 + w * 16 + quad * 4 + i;
    if (r < M) {
#pragma unroll
      for (int t = 0; t < 8; t++) h16[(long)r * H + t * 16 + cn] = f2b(aacc[t][i]);
    }
  }
}

// ---------------- fused 2-layer FFN, small-LDS variant (pre-FFN: cold input, 4 blocks/CU) ----------------
template <int BNRES>
__global__ __launch_bounds__(256) void ffn_fused(const float* __restrict__ A,
                                                 const unsigned short* __restrict__ W1T, const float* __restrict__ b1,
                                                 const unsigned short* __restrict__ W2T, const float* __restrict__ b2,
                                                 const float* __restrict__ scsh,
                                                 float* __restrict__ C, int M) {
  __shared__ unsigned short smem[FFN_SMEM];  // 18432 shorts = 36864 B
  unsigned short* Bs1 = smem;                // phase 1: 256 rows x 64-k slice
  unsigned short* Bs2 = smem + 4 * 16 * LDHW;// phase 2: 128 rows x 64-k slice

  int tid = threadIdx.x;
  int lane = tid & 63, w = tid >> 6;
  unsigned short* HsW = smem + w * 16 * LDHW;// per-wave hidden half: 16 x LDHW
  int row0 = blockIdx.x * 64;
  int mrow = lane & 15, quad = lane >> 4, cn = lane & 15;
  int arow = row0 + w * 16 + mrow;
  bool rin = arow < M;

  short8 af[4];
#pragma unroll
  for (int k0 = 0; k0 < 4; k0++) {
    int kb = k0 * 32 + quad * 8;
    floatx4 a0 = (floatx4)0.f, a1 = (floatx4)0.f;
    if (rin) {
      a0 = *(const floatx4*)&A[(long)arow * H + kb];
      a1 = *(const floatx4*)&A[(long)arow * H + kb + 4];
      if (BNRES) {
        a0 = a0 * *(const floatx4*)&scsh[kb] + *(const floatx4*)&scsh[H + kb];
        a1 = a1 * *(const floatx4*)&scsh[kb + 4] + *(const floatx4*)&scsh[H + kb + 4];
      }
    }
    af[k0] = pack8(a0, a1);
  }

  floatx4 acc1[16];
#pragma unroll
  for (int t = 0; t < 16; t++) acc1[t] = (floatx4)0.f;

  for (int ks = 0; ks < 2; ks++) {
    if (ks > 0) __syncthreads();
#pragma unroll
    for (int j = 0; j < 8; j++) {
      int chunk = j * 256 + tid;
      int n = chunk >> 3, k8 = (chunk & 7) * 8;
      *(short8*)&Bs1[n * LDK + k8] = *(const short8*)&W1T[(long)n * H + ks * 64 + k8];
    }
    __syncthreads();
#pragma unroll
    for (int t = 0; t < 16; t++) {
      int kb = quad * 8;
      short8 bf0 = *(const short8*)&Bs1[(t * 16 + mrow) * LDK + kb];
      acc1[t] = __builtin_amdgcn_mfma_f32_16x16x32_bf16(af[ks * 2], bf0, acc1[t], 0, 0, 0);
      short8 bf1 = *(const short8*)&Bs1[(t * 16 + mrow) * LDK + 32 + kb];
      acc1[t] = __builtin_amdgcn_mfma_f32_16x16x32_bf16(af[ks * 2 + 1], bf1, acc1[t], 0, 0, 0);
    }
  }
  __syncthreads();  // all waves done reading Bs1 before HsW/Bs2 overwrite it

  // hidden -> A-fragments via per-wave LDS half-buffers (intra-wave, no barriers)
  short8 hf[8];
#pragma unroll
  for (int half = 0; half < 2; half++) {
#pragma unroll
    for (int t = 0; t < 8; t++) {
      int tt = half * 8 + t;
      int cg = tt * 16 + cn;
      int cl = t * 16 + cn;
      float bb = b1[cg];
#pragma unroll
      for (int i = 0; i < 4; i++) {
        int r = quad * 4 + i;
        HsW[r * LDHW + cl] = f2b(gelu_f(acc1[tt][i] + bb));
      }
    }
#pragma unroll
    for (int k0 = 0; k0 < 4; k0++)
      hf[half * 4 + k0] = *(const short8*)&HsW[mrow * LDHW + k0 * 32 + quad * 8];
  }

#pragma unroll
  for (int j = 0; j < 4; j++) {
    int chunk = j * 256 + tid;
    int n = chunk >> 3, k8 = (chunk & 7) * 8;
    *(short8*)&Bs2[n * LDK + k8] = *(const short8*)&W2T[(long)n * H2 + k8];
  }
  __syncthreads();

  floatx4 acc2[8];
#pragma unroll
  for (int t = 0; t < 8; t++) acc2[t] = (floatx4)0.f;

  for (int ks = 0; ks < 4; ks++) {
    if (ks > 0) {
      __syncthreads();
#pragma unroll
      for (int j = 0; j < 4; j++) {
        int chunk = j * 256 + tid;
        int n = chunk >> 3, k8 = (chunk & 7) * 8;
        *(short8*)&Bs2[n * LDK + k8] = *(const short8*)&W2T[(long)n * H2 + ks * 64 + k8];
      }
      __syncthreads();
    }
    int kk = ks * 2;
#pragma unroll
    for (int t = 0; t < 8; t++) {
      int kb0 = quad * 8;
      short8 bf0 = *(const short8*)&Bs2[(t * 16 + mrow) * LDK + kb0];
      acc2[t] = __builtin_amdgcn_mfma_f32_16x16x32_bf16(hf[kk], bf0, acc2[t], 0, 0, 0);
      short8 bf1 = *(const short8*)&Bs2[(t * 16 + mrow) * LDK + 32 + kb0];
      acc2[t] = __builtin_amdgcn_mfma_f32_16x16x32_bf16(hf[kk + 1], bf1, acc2[t], 0, 0, 0);
    }
  }

#pragma unroll
  for (int t = 0; t < 8; t++) {
    int c = t * 16 + cn;
    float bb = b2[c];
    float rsc = 0.f, rsh = 0.f;
    if (BNRES) { rsc = scsh[c]; rsh = scsh[H + c]; }
#pragma unroll
    for (int i = 0; i < 4; i++) {
      int r = row0 + w * 16 + quad * 4 + i;
      if (r < M) {
        long off = (long)r * H + c;
        float v = gelu_f(acc2[t][i] + bb);
        if (BNRES) v += C[off] * rsc + rsh;
        C[off] = v;
      }
    }
  }
}

// ---------------- persistent fused 2-layer FFN (in-loop: warm input, weights LDS-resident) ----------------
// 256 blocks x 1024 threads (1 block/CU, 16 waves). Stage W1 (64KB) + W2 (64KB) once,
// one barrier, then each wave processes 16-row tiles with ZERO barriers.
// A-loads go DIRECTLY into pack8 (staging-array variants spill — see top note).
// Grid-stride tile mapping (contiguous-chunk variant aliases HBM channels — see top note).
template <int BNRES, int POOL>
__global__ __launch_bounds__(1024) void ffn_persist(const float* __restrict__ A,
                                                    const unsigned short* __restrict__ W1T, const float* __restrict__ b1,
                                                    const unsigned short* __restrict__ W2T, const float* __restrict__ b2,
                                                    const float* __restrict__ scsh,
                                                    float* __restrict__ C, float* __restrict__ pooled,
                                                    const int* __restrict__ batch, int M) {
  __shared__ unsigned short lds[78848];  // 157696 B
  int tid = threadIdx.x;
#pragma unroll
  for (int j = 0; j < 4; j++) {
    int idx = j * 1024 + tid;
    int n = idx >> 4, k8 = (idx & 15) * 8;
    *(short8*)&lds[n * 136 + k8] = *(const short8*)&W1T[n * 128 + k8];
  }
#pragma unroll
  for (int j = 0; j < 4; j++) {
    int idx = j * 1024 + tid;
    int n = idx >> 5, k8 = (idx & 31) * 8;
    *(short8*)&lds[34816 + n * 264 + k8] = *(const short8*)&W2T[n * 256 + k8];
  }
  __syncthreads();

  int lane = tid & 63, w = tid >> 6;
  int mrow = lane & 15, quad = lane >> 4, cn = lane & 15;
  unsigned short* scr = &lds[68608 + w * 640];
  int TT = (M + 15) >> 4;
  int stride = (int)(gridDim.x << 4);

  for (int tile = blockIdx.x * 16 + w; tile < TT; tile += stride) {
    int row0 = tile << 4;
    int arow = row0 + mrow;
    bool rin = arow < M;

    short8 af[4];
#pragma unroll
    for (int k0 = 0; k0 < 4; k0++) {
      int kb = k0 * 32 + quad * 8;
      floatx4 a0 = (floatx4)0.f, a1 = (floatx4)0.f;
      if (rin) {
        a0 = *(const floatx4*)&A[(long)arow * H + kb];
        a1 = *(const floatx4*)&A[(long)arow * H + kb + 4];
        if (BNRES) {
          a0 = a0 * *(const floatx4*)&scsh[kb] + *(const floatx4*)&scsh[H + kb];
          a1 = a1 * *(const floatx4*)&scsh[kb + 4] + *(const floatx4*)&scsh[H + kb + 4];
        }
      }
      af[k0] = pack8(a0, a1);
    }

    floatx4 acc2[8];
#pragma unroll
    for (int t = 0; t < 8; t++) acc2[t] = (floatx4)0.f;

#pragma unroll
    for (int p = 0; p < 8; p++) {
      // phase 1: hidden tiles t = 2p, 2p+1 (32 hidden cols), K=128
#pragma unroll
      for (int u = 0; u < 2; u++) {
        int t = p * 2 + u;
        floatx4 a = (floatx4)0.f;
#pragma unroll
        for (int k = 0; k < 4; k++) {
          short8 bf = *(const short8*)&lds[(t * 16 + mrow) * 136 + k * 32 + quad * 8];
          a = __builtin_amdgcn_mfma_f32_16x16x32_bf16(af[k], bf, a, 0, 0, 0);
        }
        float bb = b1[t * 16 + cn];
#pragma unroll
        for (int i = 0; i < 4; i++)
          scr[(quad * 4 + i) * 40 + u * 16 + cn] = f2b(gelu_f(a[i] + bb));
      }
      // transpose readback: A-frag for hidden k-chunk p (row=mrow, k=quad*8..+7)
      short8 hf = *(const short8*)&scr[mrow * 40 + quad * 8];
      // phase 2: accumulate this 32-k chunk into all 8 output col-tiles
#pragma unroll
      for (int ct = 0; ct < 8; ct++) {
        short8 bf = *(const short8*)&lds[34816 + (ct * 16 + mrow) * 264 + p * 32 + quad * 8];
        acc2[ct] = __builtin_amdgcn_mfma_f32_16x16x32_bf16(hf, bf, acc2[ct], 0, 0, 0);
      }
    }

    // epilogue (+ optional fused pooling)
    int g0 = 0; bool same = true;
    if (POOL) {
      int rl = row0 + 15; if (rl >= M) rl = M - 1;
      g0 = batch[row0];
      same = (batch[rl] == g0);
    }
#pragma unroll
    for (int t = 0; t < 8; t++) {
      int c = t * 16 + cn;
      float bb = b2[c];
      float rsc = 0.f, rsh = 0.f;
      if (BNRES) { rsc = scsh[c]; rsh = scsh[H + c]; }
      float s = 0.f;
#pragma unroll
      for (int i = 0; i < 4; i++) {
        int r = row0 + quad * 4 + i;
        float v = 0.f;
        if (r < M) {
          long off = (long)r * H + c;
          v = gelu_f(acc2[t][i] + bb);
          if (BNRES) v += C[off] * rsc + rsh;
          C[off] = v;
          if (POOL && !same) atomicAdd(&pooled[batch[r] * H + c], v);
        }
        s += v;
      }
      if (POOL && same) {
        s += __shfl_xor(s, 16);
        s += __shfl_xor(s, 32);
        if (quad == 0) atomicAdd(&pooled[g0 * H + c], s);
      }
    }
  }
}

// ---------------- parallel 64-row MLP stages (vn / post) ----------------
template <int BN, int UVN>
__global__ __launch_bounds__(256) void mlp64_l1(const float* __restrict__ vn, const float* __restrict__ pooled,
                                                const float* __restrict__ counts,
                                                const float* __restrict__ W1, const float* __restrict__ b1,
                                                const float* __restrict__ g1, const float* __restrict__ be1,
                                                float* __restrict__ h1) {
  __shared__ float u[64 * H];
  __shared__ float red[8 * 64];
  int t = threadIdx.x;
  for (int idx = t; idx < 64 * H; idx += 256) {
    float v = pooled[idx];
    if (UVN) v = vn[idx] + v / fmaxf(counts[idx >> 7], 1.0f);
    u[idx] = v;
  }
  __syncthreads();
  int tc = t & 63, tg = t >> 6;
  int c = blockIdx.x * 64 + tc;
  float acc[16];
  float bj = b1[c];
#pragma unroll
  for (int g = 0; g < 16; g++) acc[g] = bj;
  for (int k0 = 0; k0 < H; k0 += 4) {
    float w0 = W1[(k0 + 0) * H2 + c];
    float w1 = W1[(k0 + 1) * H2 + c];
    float w2 = W1[(k0 + 2) * H2 + c];
    float w3 = W1[(k0 + 3) * H2 + c];
#pragma unroll
    for (int g = 0; g < 16; g++) {
      float4 v = *(const float4*)&u[(tg * 16 + g) * H + k0];
      acc[g] += v.x * w0 + v.y * w1 + v.z * w2 + v.w * w3;
    }
  }
  float sc = 1.f, sh = 0.f;
  if (BN) {
    float s = 0.f, s2 = 0.f;
#pragma unroll
    for (int g = 0; g < 16; g++) { s += acc[g]; s2 += acc[g] * acc[g]; }
    red[tg * 64 + tc] = s;
    red[256 + tg * 64 + tc] = s2;
    __syncthreads();
    float st = red[tc] + red[64 + tc] + red[128 + tc] + red[192 + tc];
    float st2 = red[256 + tc] + red[320 + tc] + red[384 + tc] + red[448 + tc];
    float m = st * (1.f / 64.f);
    float var = st2 * (1.f / 64.f) - m * m;
    sc = rsqrtf(var + 1e-5f) * g1[c];
    sh = be1[c] - m * sc;
  }
#pragma unroll
  for (int g = 0; g < 16; g++) h1[(tg * 16 + g) * H2 + c] = gelu_f(acc[g] * sc + sh);
}

template <int BN>
__global__ __launch_bounds__(256) void mlp64_l2(const float* __restrict__ h1,
                                                const float* __restrict__ W2, const float* __restrict__ b2,
                                                const float* __restrict__ g2, const float* __restrict__ be2,
                                                float* __restrict__ outp) {
  __shared__ float red[8 * 64];
  int t = threadIdx.x;
  int tc = t & 63, tg = t >> 6;
  int c = blockIdx.x * 64 + tc;
  float acc[16];
  float bj = b2[c];
#pragma unroll
  for (int g = 0; g < 16; g++) acc[g] = bj;
  for (int k0 = 0; k0 < H2; k0 += 4) {
    float w0 = W2[(k0 + 0) * H + c];
    float w1 = W2[(k0 + 1) * H + c];
    float w2 = W2[(k0 + 2) * H + c];
    float w3 = W2[(k0 + 3) * H + c];
#pragma unroll
    for (int g = 0; g < 16; g++) {
      float4 v = *(const float4*)&h1[(tg * 16 + g) * H2 + k0];
      acc[g] += v.x * w0 + v.y * w1 + v.z * w2 + v.w * w3;
    }
  }
  float sc = 1.f, sh = 0.f;
  if (BN) {
    float s = 0.f, s2 = 0.f;
#pragma unroll
    for (int g = 0; g < 16; g++) { s += acc[g]; s2 += acc[g] * acc[g]; }
    red[tg * 64 + tc] = s;
    red[256 + tg * 64 + tc] = s2;
    __syncthreads();
    float st = red[tc] + red[64 + tc] + red[128 + tc] + red[192 + tc];
    float st2 = red[256 + tc] + red[320 + tc] + red[384 + tc] + red[448 + tc];
    float m = st * (1.f / 64.f);
    float var = st2 * (1.f / 64.f) - m * m;
    sc = rsqrtf(var + 1e-5f) * g2[c];
    sh = be2[c] - m * sc;
  }
#pragma unroll
  for (int g = 0; g < 16; g++) outp[(tg * 16 + g) * H + c] = gelu_f(acc[g] * sc + sh);
}

// ---------------- host launch ----------------

extern "C" void kernel_launch(void* const* d_in, const int* in_sizes, int n_in,
                              void* d_out, int out_size, void* d_ws, size_t ws_size,
                              hipStream_t stream) {
  const float* x_in   = (const float*)d_in[0];
  const int*   edge   = (const int*)d_in[1];
  const int*   batch  = (const int*)d_in[2];
  const float* pre_W1 = (const float*)d_in[3];
  const float* pre_b1 = (const float*)d_in[4];
  const float* pre_W2 = (const float*)d_in[5];
  const float* pre_b2 = (const float*)d_in[6];
  const float* conv_W = (const float*)d_in[7];
  const float* conv_b = (const float*)d_in[8];
  const float* bn_g   = (const float*)d_in[9];
  const float* bn_b   = (const float*)d_in[10];
  const float* ffn_W1 = (const float*)d_in[11];
  const float* ffn_b1 = (const float*)d_in[12];
  const float* ffn_W2 = (const float*)d_in[13];
  const float* ffn_b2 = (const float*)d_in[14];
  const float* vn_W1  = (const float*)d_in[15];
  const float* vn_b1  = (const float*)d_in[16];
  const float* vn_g1  = (const float*)d_in[17];
  const float* vn_be1 = (const float*)d_in[18];
  const float* vn_W2  = (const float*)d_in[19];
  const float* vn_b2  = (const float*)d_in[20];
  const float* vn_g2  = (const float*)d_in[21];
  const float* vn_be2 = (const float*)d_in[22];
  const float* vn_emb = (const float*)d_in[23];
  const float* post_W1= (const float*)d_in[24];
  const float* post_b1= (const float*)d_in[25];
  const float* post_W2= (const float*)d_in[26];
  const float* post_b2= (const float*)d_in[27];
  float* out = (float*)d_out;

  const int N    = in_sizes[2];
  const int E    = in_sizes[1] / 2;
  const int G    = out_size / H;
  const int HOPS = in_sizes[7] / (H * H);
  const int NH   = N * H;

  // workspace layout
  float* w = (float*)d_ws;
  float* buf_x  = w;  w += NH;
  float* buf_t  = w;  w += N * H2;
  unsigned short* buf_h16 = (unsigned short*)buf_t;
  float* dinv   = w;  w += N;
  float* counts = w;  w += G;
  float* stats  = w;  w += 2 * H;
  float* scsh   = w;  w += 2 * H;
  float* pooled = w;  w += G * H;
  float* vn     = w;  w += G * H;
  float* mlp_h1 = w;  w += G * H2;
  float* csr_norm = w; w += E;
  int* iw = (int*)w;
  int* cnt      = iw;  iw += N;
  int* row_ptr  = iw;  iw += N + 1;
  int* cursor   = iw;  iw += N;
  int* csr_src  = iw;  iw += E;
  int* blockSum = iw;  iw += 1024;
  int* blockOff = iw;  iw += 1024;
  unsigned short* wt = (unsigned short*)iw;
  unsigned short* preW1T = wt;  wt += H * H2;
  unsigned short* preW2T = wt;  wt += H2 * H;
  unsigned short* convT  = wt;  wt += HOPS * H * H;
  unsigned short* ffn1T  = wt;  wt += HOPS * H * H2;
  unsigned short* ffn2T  = wt;  wt += HOPS * H2 * H;

  const int* src = edge;
  const int* dst = edge + E;

  int gE  = (E + 255) / 256;
  int gM  = (N + 63) / 64;
  int nb  = (N + 1023) / 1024;
  float invN = 1.0f / (float)N;

  // weight transposes
  transpose_w<<<(H * H2 + 255) / 256, 256, 0, stream>>>(pre_W1, preW1T, H, H2, H * H2);
  transpose_w<<<(H2 * H + 255) / 256, 256, 0, stream>>>(pre_W2, preW2T, H2, H, H2 * H);
  transpose_w<<<(HOPS * H * H + 255) / 256, 256, 0, stream>>>(conv_W, convT, H, H, HOPS * H * H);
  transpose_w<<<(HOPS * H * H2 + 255) / 256, 256, 0, stream>>>(ffn_W1, ffn1T, H, H2, HOPS * H * H2);
  transpose_w<<<(HOPS * H2 * H + 255) / 256, 256, 0, stream>>>(ffn_W2, ffn2T, H2, H, HOPS * H2 * H);

  // CSR build + dinv
  hipMemsetAsync(cnt, 0, N * sizeof(int), stream);
  hist_kernel<<<gE, 256, 0, stream>>>(cnt, dst, E);
  scan_a<<<nb, 256, 0, stream>>>(cnt, row_ptr, blockSum, dinv, N);
  scan_b<<<1, 1024, 0, stream>>>(blockSum, blockOff, nb, row_ptr, N, E);
  scan_c<<<nb, 256, 0, stream>>>(row_ptr, blockOff, N);
  hipMemsetAsync(cursor, 0, N * sizeof(int), stream);
  build_csr_kernel<<<gE, 256, 0, stream>>>(src, dst, row_ptr, cursor, dinv, csr_src, csr_norm, E);

  // graph counts, vn init
  hipMemsetAsync(counts, 0, G * sizeof(float), stream);
  count_kernel<<<(N + 256 * 16 - 1) / (256 * 16), 256, 0, stream>>>(counts, batch, N, G);
  vn_init_kernel<<<(G * H + 255) / 256, 256, 0, stream>>>(vn, vn_emb, G * H);

  // pre-FFNN: cold x_in -> many-block small-LDS variant (more memory parallelism)
  ffn_fused<0><<<gM, 256, 0, stream>>>(x_in, preW1T, pre_b1, preW2T, pre_b2, nullptr, buf_x, N);

  for (int i = 0; i < HOPS; i++) {
    // GCN: h16 = bf16( (x + vn[batch]) @ W ); block 0 zeroes stats for gather
    conv_gemm<<<gM, 256, 0, stream>>>(buf_x, convT + i * H * H, vn, batch, buf_h16, stats, N);
    // x = x + vn[batch] + bias + selfloop + gathered edges; BN stats fused
    gather_agg<<<(N + 31) / 32, 256, 0, stream>>>(buf_h16, csr_src, csr_norm, row_ptr, dinv, vn, batch,
                                                  conv_b + i * H, buf_x, stats, N);
    // stats -> scale/shift; also zeroes pooled for the ffn_persist POOL atomics
    bn_finalize_kernel<<<1, 128, 0, stream>>>(stats, bn_g + i * H, bn_b + i * H, scsh, invN, pooled, G * H);
    // fused FFN: x = gelu(gelu(bn(x)@W1+b1)@W2+b2) + bn(x); pooling fused into epilogue
    ffn_persist<1, 1><<<256, 1024, 0, stream>>>(buf_x, ffn1T + i * H * H2, ffn_b1 + i * H2,
                                                ffn2T + i * H2 * H, ffn_b2 + i * H, scsh,
                                                buf_x, pooled, batch, N);
    // virtual node update
    if (i < HOPS - 1) {
      mlp64_l1<1, 1><<<H2 / 64, 256, 0, stream>>>(vn, pooled, counts,
                                                  vn_W1 + i * H * H2, vn_b1 + i * H2, vn_g1 + i * H2, vn_be1 + i * H2,
                                                  mlp_h1);
      mlp64_l2<1><<<H / 64, 256, 0, stream>>>(mlp_h1, vn_W2 + i * H2 * H, vn_b2 + i * H, vn_g2 + i * H, vn_be2 + i * H, vn);
    }
  }

  // final global_add_pool came fused from the last ffn_persist; post-FFNN
  mlp64_l1<0, 0><<<H2 / 64, 256, 0, stream>>>(nullptr, pooled, nullptr, post_W1, post_b1, nullptr, nullptr, mlp_h1);
  mlp64_l2<0><<<H / 64, 256, 0, stream>>>(mlp_h1, post_W2, post_b2, nullptr, nullptr, out);
}

// Round 14
// 1640.806 us; speedup vs baseline: 1.2032x; 1.0530x over previous
//
#include <hip/hip_runtime.h>
#include <math.h>

#define H 128
#define H2 256
#define LDC 136   // LDS row stride (bf16) for conv weight rows (128 k)
#define LDK 72    // LDS row stride (bf16) for 64-wide k rows (ffn_fused)
#define LDHW 136  // LDS row stride (bf16) for per-wave hidden half (ffn_fused)
#define FFN_SMEM (H2 * LDK)  // 18432 shorts = 36864 B -> 4 blocks/CU
// persistent FFN LDS layout (shorts):
//   W1s: [256][136]  = 34816          (rows: hidden col n, 128 k + pad8)
//   W2s: [128][264]  = 33792 @34816   (rows: out col c, 256 k + pad8)
//   scr: 16 waves x [16][40] = 10240 @68608  (per-wave transpose buffer)
// total 78848 shorts = 157696 B  (<= 160 KiB/CU, 1 block/CU, 16 waves)
// REG DISCIPLINE (round-3/6): 128 unified VGPR+AGPR/wave at 16 waves/CU;
// A-loads DIRECTLY into pack8, no staging arrays with cross-MFMA liveness.
// TILE MAPPING (round-8): grid-stride keeps HBM channel interleave even.
// X-PRECISION (rounds 10-12, REFUTED): bf16 x carrier regressed the FFN.
// WRITE MODEL (round-13): ffn WRITE excess over logical = fused POOL
// device-scope atomics (~57MB = 800K x 64B sectors); C-writes themselves
// are clean (ffn_fused no-pool: WRITE == logical).
// RESIDUAL (round-14): epilogue residual bn(x) recovered from the
// still-live af fragments via a scr transpose (af is live through all
// MFMA phases anyway -> zero added peak pressure) — deletes the 51MB
// C re-read per in-loop dispatch.

typedef __attribute__((ext_vector_type(8))) short short8;
typedef __attribute__((ext_vector_type(4))) float floatx4;

// fast GELU: x * sigmoid(1.5957691*x*(1+0.044715*x^2)); max |dev| from exact erf-GELU ~1e-3
__device__ __forceinline__ float gelu_f(float x) {
  float t = 1.59576912161f * x * fmaf(0.044715f, x * x, 1.0f);
  return x / (1.0f + __expf(-t));
}

__device__ __forceinline__ unsigned short f2b(float f) {
  union { float f; unsigned u; } c; c.f = f;
  unsigned r = c.u + 0x7fffu + ((c.u >> 16) & 1u);
  return (unsigned short)(r >> 16);
}

__device__ __forceinline__ float b2f(unsigned short u) {
  union { unsigned u; float f; } c; c.u = ((unsigned)u) << 16; return c.f;
}

__device__ __forceinline__ float blo(unsigned u) { return __uint_as_float(u << 16); }
__device__ __forceinline__ float bhi(unsigned u) { return __uint_as_float(u & 0xffff0000u); }

__device__ __forceinline__ short8 pack8(floatx4 a, floatx4 b) {
  union { short8 v; unsigned short s[8]; } u;
  u.s[0] = f2b(a.x); u.s[1] = f2b(a.y); u.s[2] = f2b(a.z); u.s[3] = f2b(a.w);
  u.s[4] = f2b(b.x); u.s[5] = f2b(b.y); u.s[6] = f2b(b.z); u.s[7] = f2b(b.w);
  return u.v;
}

// ---------------- weight transpose+convert: W[b][K][N] fp32 -> WT[b][N][K] bf16 ----------------
__global__ __launch_bounds__(256) void transpose_w(const float* __restrict__ W, unsigned short* __restrict__ WT,
                                                   int K, int Ncol, int total) {
  int i = blockIdx.x * 256 + threadIdx.x;
  if (i >= total) return;
  int kn = K * Ncol;
  int b = i / kn, r = i - b * kn;
  int k = r / Ncol, n = r - k * Ncol;
  WT[b * kn + n * K + k] = f2b(W[i]);
}

// ---------------- CSR build ----------------

__global__ __launch_bounds__(256) void hist_kernel(int* __restrict__ cnt, const int* __restrict__ dst, int E) {
  int i = blockIdx.x * 256 + threadIdx.x;
  if (i < E) atomicAdd(&cnt[dst[i]], 1);
}

__global__ __launch_bounds__(256) void scan_a(const int* __restrict__ cnt, int* __restrict__ row_ptr,
                                              int* __restrict__ blockSum, float* __restrict__ dinv, int N) {
  __shared__ int ls[256];
  int t = threadIdx.x;
  int idx = blockIdx.x * 1024 + t * 4;
  int4 v = make_int4(0, 0, 0, 0);
  if (idx + 3 < N) v = *(const int4*)&cnt[idx];
  else {
    if (idx + 0 < N) v.x = cnt[idx + 0];
    if (idx + 1 < N) v.y = cnt[idx + 1];
    if (idx + 2 < N) v.z = cnt[idx + 2];
    if (idx + 3 < N) v.w = cnt[idx + 3];
  }
  if (idx + 0 < N) dinv[idx + 0] = rsqrtf((float)v.x + 1.0f);
  if (idx + 1 < N) dinv[idx + 1] = rsqrtf((float)v.y + 1.0f);
  if (idx + 2 < N) dinv[idx + 2] = rsqrtf((float)v.z + 1.0f);
  if (idx + 3 < N) dinv[idx + 3] = rsqrtf((float)v.w + 1.0f);
  int s = v.x + v.y + v.z + v.w;
  ls[t] = s;
  __syncthreads();
  for (int off = 1; off < 256; off <<= 1) {
    int a = (t >= off) ? ls[t - off] : 0;
    __syncthreads();
    ls[t] += a;
    __syncthreads();
  }
  int p = ls[t] - s;
  if (t == 255) blockSum[blockIdx.x] = ls[255];
  if (idx + 0 < N) row_ptr[idx + 0] = p;  p += v.x;
  if (idx + 1 < N) row_ptr[idx + 1] = p;  p += v.y;
  if (idx + 2 < N) row_ptr[idx + 2] = p;  p += v.z;
  if (idx + 3 < N) row_ptr[idx + 3] = p;
}

__global__ __launch_bounds__(1024) void scan_b(const int* __restrict__ blockSum, int* __restrict__ blockOff,
                                               int nb, int* __restrict__ row_ptr, int N, int E) {
  __shared__ int ls[1024];
  int t = threadIdx.x;
  int s = (t < nb) ? blockSum[t] : 0;
  ls[t] = s;
  __syncthreads();
  for (int off = 1; off < 1024; off <<= 1) {
    int a = (t >= off) ? ls[t - off] : 0;
    __syncthreads();
    ls[t] += a;
    __syncthreads();
  }
  if (t < nb) blockOff[t] = ls[t] - s;
  if (t == 0) row_ptr[N] = E;
}

__global__ __launch_bounds__(256) void scan_c(int* __restrict__ row_ptr, const int* __restrict__ blockOff, int N) {
  int t = threadIdx.x;
  int idx = blockIdx.x * 1024 + t * 4;
  int off = blockOff[blockIdx.x];
  if (off == 0) return;
  if (idx + 3 < N) {
    int4 v = *(const int4*)&row_ptr[idx];
    v.x += off; v.y += off; v.z += off; v.w += off;
    *(int4*)&row_ptr[idx] = v;
  } else {
    if (idx + 0 < N) row_ptr[idx + 0] += off;
    if (idx + 1 < N) row_ptr[idx + 1] += off;
    if (idx + 2 < N) row_ptr[idx + 2] += off;
    if (idx + 3 < N) row_ptr[idx + 3] += off;
  }
}

__global__ __launch_bounds__(256) void build_csr_kernel(const int* __restrict__ src, const int* __restrict__ dst,
                                                        const int* __restrict__ row_ptr, int* __restrict__ cursor,
                                                        const float* __restrict__ dinv,
                                                        int* __restrict__ csr_src, float* __restrict__ csr_norm,
                                                        int E) {
  int i = blockIdx.x * 256 + threadIdx.x;
  if (i < E) {
    int s = src[i], d = dst[i];
    int pos = row_ptr[d] + atomicAdd(&cursor[d], 1);
    csr_src[pos] = s;
    csr_norm[pos] = dinv[s] * dinv[d];
  }
}

// ---------------- small setup kernels ----------------

__global__ __launch_bounds__(256) void count_kernel(float* counts, const int* __restrict__ batch, int N, int G) {
  __shared__ float hist[256];
  int t = threadIdx.x;
  if (t < G) hist[t] = 0.f;
  __syncthreads();
  int i0 = (blockIdx.x * 256 + t) * 16;
  int cur = -1; float run = 0.f;
  for (int j = 0; j < 16; j++) {
    int i = i0 + j;
    if (i < N) {
      int b = batch[i];
      if (b == cur) run += 1.f;
      else { if (cur >= 0) atomicAdd(&hist[cur], run); cur = b; run = 1.f; }
    }
  }
  if (cur >= 0) atomicAdd(&hist[cur], run);
  __syncthreads();
  if (t < G && hist[t] != 0.f) atomicAdd(&counts[t], hist[t]);
}

__global__ __launch_bounds__(256) void vn_init_kernel(float* vn, const float* __restrict__ emb, int n) {
  int i = blockIdx.x * 256 + threadIdx.x;
  if (i < n) vn[i] = emb[i & (H - 1)];
}

// ---------------- fused gather aggregation (bf16 h) + BN stats ----------------
// 2 nodes per wave-instruction (half-wave per node, 4 ch/lane). 8 nodes/wave as 4 pairs.
__global__ __launch_bounds__(256) void gather_agg(const unsigned short* __restrict__ h, const int* __restrict__ csr_src,
                                                  const float* __restrict__ csr_norm, const int* __restrict__ row_ptr,
                                                  const float* __restrict__ dinv, const float* __restrict__ vn,
                                                  const int* __restrict__ batch, const float* __restrict__ bias,
                                                  float* __restrict__ x, float* __restrict__ stats, int N) {
  __shared__ float sred[4 * H];
  __shared__ float qred[4 * H];
  int w = threadIdx.x >> 6, lane = threadIdx.x & 63;
  int hh = lane >> 5;          // which node of the pair
  int li = lane & 31;
  int c = li * 4;              // 4 channels per lane
  floatx4 bi = *(const floatx4*)&bias[c];
  int base = blockIdx.x * 32 + w * 8;

  int nd[4]; bool act[4];
#pragma unroll
  for (int j = 0; j < 4; j++) {
    int n0 = base + 2 * j + hh;
    act[j] = n0 < N;
    nd[j] = act[j] ? n0 : (N - 1);
  }
  int beg[4], end[4], bt[4];
  float dd[4];
#pragma unroll
  for (int j = 0; j < 4; j++) { beg[j] = row_ptr[nd[j]]; end[j] = row_ptr[nd[j] + 1]; }
#pragma unroll
  for (int j = 0; j < 4; j++) { bt[j] = batch[nd[j]]; float di = dinv[nd[j]]; dd[j] = di * di; }
  floatx4 xo[4]; uint2 hs[4];
#pragma unroll
  for (int j = 0; j < 4; j++) {
    xo[j] = *(const floatx4*)&x[(long)nd[j] * H + c];
    hs[j] = *(const uint2*)&h[(long)nd[j] * H + c];
  }
  float a0[4], a1[4], a2[4], a3[4];
#pragma unroll
  for (int j = 0; j < 4; j++) {
    a0[j] = blo(hs[j].x) * dd[j];
    a1[j] = bhi(hs[j].x) * dd[j];
    a2[j] = blo(hs[j].y) * dd[j];
    a3[j] = bhi(hs[j].y) * dd[j];
  }

#define GROUP_CSR(j, eb, sv, nv)                      \
  int sv; float nv;                                   \
  {                                                   \
    int idx_ = beg[j] + (eb) + li;                    \
    bool vld_ = (li < 8) && (idx_ < end[j]);          \
    int sidx_ = vld_ ? idx_ : 0;                      \
    sv = csr_src[sidx_];                              \
    nv = vld_ ? csr_norm[sidx_] : 0.f;                \
  }

#define GROUP_GACC(j, sv, nv)                         \
  {                                                   \
    uint2 u_[8]; float wg_[8];                        \
    _Pragma("unroll")                                 \
    for (int ii = 0; ii < 8; ii++) {                  \
      wg_[ii] = __shfl(nv, hh * 32 + ii);             \
      int si_ = __shfl(sv, hh * 32 + ii);             \
      u_[ii] = *(const uint2*)&h[(long)si_ * H + c];  \
    }                                                 \
    _Pragma("unroll")                                 \
    for (int ii = 0; ii < 8; ii++) {                  \
      a0[j] += blo(u_[ii].x) * wg_[ii];               \
      a1[j] += bhi(u_[ii].x) * wg_[ii];               \
      a2[j] += blo(u_[ii].y) * wg_[ii];               \
      a3[j] += bhi(u_[ii].y) * wg_[ii];               \
    }                                                 \
  }

  // first edge-group of all 4 pairs: csr loads all issued first
  {
    GROUP_CSR(0, 0, sv0, nv0)
    GROUP_CSR(1, 0, sv1, nv1)
    GROUP_CSR(2, 0, sv2, nv2)
    GROUP_CSR(3, 0, sv3, nv3)
    GROUP_GACC(0, sv0, nv0)
    GROUP_GACC(1, sv1, nv1)
    GROUP_GACC(2, sv2, nv2)
    GROUP_GACC(3, sv3, nv3)
  }

  // tails (deg > 8): interleave needed groups across pairs per round
  int dmx[4];
#pragma unroll
  for (int j = 0; j < 4; j++) {
    int d = end[j] - beg[j];
    int dx = __shfl_xor(d, 32);
    dmx[j] = d > dx ? d : dx;      // wave-uniform per pair
  }
  int dall = dmx[0];
  if (dmx[1] > dall) dall = dmx[1];
  if (dmx[2] > dall) dall = dmx[2];
  if (dmx[3] > dall) dall = dmx[3];
  for (int eb = 8; eb < dall; eb += 8) {
#pragma unroll
    for (int j = 0; j < 4; j++) {
      if (eb < dmx[j]) {
        GROUP_CSR(j, eb, svt, nvt)
        GROUP_GACC(j, svt, nvt)
      }
    }
  }
#undef GROUP_CSR
#undef GROUP_GACC

  // combine: + x_old + vn[batch] + bias, store, BN stats
  float s0 = 0.f, s1 = 0.f, s2 = 0.f, s3 = 0.f;
  float q0 = 0.f, q1 = 0.f, q2 = 0.f, q3 = 0.f;
#pragma unroll
  for (int j = 0; j < 4; j++) {
    floatx4 vv = *(const floatx4*)&vn[bt[j] * H + c];
    float r0 = a0[j] + xo[j].x + vv.x + bi.x;
    float r1 = a1[j] + xo[j].y + vv.y + bi.y;
    float r2 = a2[j] + xo[j].z + vv.z + bi.z;
    float r3 = a3[j] + xo[j].w + vv.w + bi.w;
    if (act[j]) {
      floatx4 rv = {r0, r1, r2, r3};
      *(floatx4*)&x[(long)nd[j] * H + c] = rv;
      s0 += r0; q0 += r0 * r0;
      s1 += r1; q1 += r1 * r1;
      s2 += r2; q2 += r2 * r2;
      s3 += r3; q3 += r3 * r3;
    }
  }
  // cross-half reduce, then per-block LDS reduce + one atomic per column
  s0 += __shfl_xor(s0, 32); s1 += __shfl_xor(s1, 32);
  s2 += __shfl_xor(s2, 32); s3 += __shfl_xor(s3, 32);
  q0 += __shfl_xor(q0, 32); q1 += __shfl_xor(q1, 32);
  q2 += __shfl_xor(q2, 32); q3 += __shfl_xor(q3, 32);
  if (hh == 0) {
    floatx4 sv4 = {s0, s1, s2, s3};
    floatx4 qv4 = {q0, q1, q2, q3};
    *(floatx4*)&sred[w * H + c] = sv4;
    *(floatx4*)&qred[w * H + c] = qv4;
  }
  __syncthreads();
  int t = threadIdx.x;
  if (t < H) {
    float s = sred[t] + sred[H + t] + sred[2 * H + t] + sred[3 * H + t];
    if (s != 0.f) atomicAdd(&stats[t], s);
  } else {
    int cc = t - H;
    float q = qred[cc] + qred[H + cc] + qred[2 * H + cc] + qred[3 * H + cc];
    if (q != 0.f) atomicAdd(&stats[H + cc], q);
  }
}

// ---------------- BN finalize (stats -> scale/shift) + pooled zeroing ----------------
__global__ __launch_bounds__(128) void bn_finalize_kernel(const float* __restrict__ stats, const float* __restrict__ g,
                                                          const float* __restrict__ b, float* __restrict__ scsh,
                                                          float invN, float* __restrict__ pooled, int GH) {
  int c = threadIdx.x;
  float m = stats[c] * invN;
  float v = stats[H + c] * invN - m * m;
  float sc = rsqrtf(v + 1e-5f) * g[c];
  scsh[c] = sc;
  scsh[H + c] = b[c] - m * sc;
  for (int i = c; i < GH; i += 128) pooled[i] = 0.f;
}

// ---------------- conv GEMM: B staged once in LDS, A loads hoisted, 1 barrier ----------------
// Block 0 also zeroes 'stats' for the gather_agg that follows.
__global__ __launch_bounds__(256) void conv_gemm(const float* __restrict__ x, const unsigned short* __restrict__ BT,
                                                 const float* __restrict__ vn, const int* __restrict__ batch,
                                                 unsigned short* __restrict__ h16, float* __restrict__ stats, int M) {
  __shared__ unsigned short Bs[H * LDC];  // 34816 B
  int tid = threadIdx.x;
  if (blockIdx.x == 0) stats[tid] = 0.f;  // 2*H == 256 == blockDim
  int lane = tid & 63, w = tid >> 6;
  int row0 = blockIdx.x * 64;
  int mrow = lane & 15, quad = lane >> 4, cn = lane & 15;
  int arow = row0 + w * 16 + mrow;
  bool rin = arow < M;
  int b = rin ? batch[arow] : 0;

  // x loads first (long-latency), then weight staging, then vn (small, L2-hot)
  floatx4 xr[8];
#pragma unroll
  for (int k0 = 0; k0 < 4; k0++) {
    int kb = k0 * 32 + quad * 8;
    xr[2 * k0]     = rin ? *(const floatx4*)&x[(long)arow * H + kb]     : (floatx4)0.f;
    xr[2 * k0 + 1] = rin ? *(const floatx4*)&x[(long)arow * H + kb + 4] : (floatx4)0.f;
  }

#pragma unroll
  for (int j = 0; j < 8; j++) {
    int chunk = j * 256 + tid;
    int n = chunk >> 4, k8 = (chunk & 15) * 8;
    *(short8*)&Bs[n * LDC + k8] = *(const short8*)&BT[(long)n * H + k8];
  }

  short8 af[4];
#pragma unroll
  for (int k0 = 0; k0 < 4; k0++) {
    int kb = k0 * 32 + quad * 8;
    floatx4 a0 = xr[2 * k0], a1 = xr[2 * k0 + 1];
    if (rin) {
      a0 = a0 + *(const floatx4*)&vn[b * H + kb];
      a1 = a1 + *(const floatx4*)&vn[b * H + kb + 4];
    }
    af[k0] = pack8(a0, a1);
  }
  __syncthreads();

  floatx4 aacc[8];
#pragma unroll
  for (int t = 0; t < 8; t++) {
    floatx4 a = (floatx4)0.f;
#pragma unroll
    for (int k0 = 0; k0 < 4; k0++) {
      int kb = k0 * 32 + quad * 8;
      short8 bf = *(const short8*)&Bs[(t * 16 + mrow) * LDC + kb];
      a = __builtin_amdgcn_mfma_f32_16x16x32_bf16(af[k0], bf, a, 0, 0, 0);
    }
    aacc[t] = a;
  }
  // i-outer / t-inner store order: per-row chunks issued consecutively -> line combining
#pragma unroll
  for (int i = 0; i < 4; i++) {
    int r = row0 + w * 16 + quad * 4 + i;
    if (r < M) {
#pragma unroll
      for (int t = 0; t < 8; t++) h16[(long)r * H + t * 16 + cn] = f2b(aacc[t][i]);
    }
  }
}

// ---------------- fused 2-layer FFN, small-LDS variant (pre-FFN: cold input, 4 blocks/CU) ----------------
template <int BNRES>
__global__ __launch_bounds__(256) void ffn_fused(const float* __restrict__ A,
                                                 const unsigned short* __restrict__ W1T, const float* __restrict__ b1,
                                                 const unsigned short* __restrict__ W2T, const float* __restrict__ b2,
                                                 const float* __restrict__ scsh,
                                                 float* __restrict__ C, int M) {
  __shared__ unsigned short smem[FFN_SMEM];  // 18432 shorts = 36864 B
  unsigned short* Bs1 = smem;                // phase 1: 256 rows x 64-k slice
  unsigned short* Bs2 = smem + 4 * 16 * LDHW;// phase 2: 128 rows x 64-k slice

  int tid = threadIdx.x;
  int lane = tid & 63, w = tid >> 6;
  unsigned short* HsW = smem + w * 16 * LDHW;// per-wave hidden half: 16 x LDHW
  int row0 = blockIdx.x * 64;
  int mrow = lane & 15, quad = lane >> 4, cn = lane & 15;
  int arow = row0 + w * 16 + mrow;
  bool rin = arow < M;

  short8 af[4];
#pragma unroll
  for (int k0 = 0; k0 < 4; k0++) {
    int kb = k0 * 32 + quad * 8;
    floatx4 a0 = (floatx4)0.f, a1 = (floatx4)0.f;
    if (rin) {
      a0 = *(const floatx4*)&A[(long)arow * H + kb];
      a1 = *(const floatx4*)&A[(long)arow * H + kb + 4];
      if (BNRES) {
        a0 = a0 * *(const floatx4*)&scsh[kb] + *(const floatx4*)&scsh[H + kb];
        a1 = a1 * *(const floatx4*)&scsh[kb + 4] + *(const floatx4*)&scsh[H + kb + 4];
      }
    }
    af[k0] = pack8(a0, a1);
  }

  floatx4 acc1[16];
#pragma unroll
  for (int t = 0; t < 16; t++) acc1[t] = (floatx4)0.f;

  for (int ks = 0; ks < 2; ks++) {
    if (ks > 0) __syncthreads();
#pragma unroll
    for (int j = 0; j < 8; j++) {
      int chunk = j * 256 + tid;
      int n = chunk >> 3, k8 = (chunk & 7) * 8;
      *(short8*)&Bs1[n * LDK + k8] = *(const short8*)&W1T[(long)n * H + ks * 64 + k8];
    }
    __syncthreads();
#pragma unroll
    for (int t = 0; t < 16; t++) {
      int kb = quad * 8;
      short8 bf0 = *(const short8*)&Bs1[(t * 16 + mrow) * LDK + kb];
      acc1[t] = __builtin_amdgcn_mfma_f32_16x16x32_bf16(af[ks * 2], bf0, acc1[t], 0, 0, 0);
      short8 bf1 = *(const short8*)&Bs1[(t * 16 + mrow) * LDK + 32 + kb];
      acc1[t] = __builtin_amdgcn_mfma_f32_16x16x32_bf16(af[ks * 2 + 1], bf1, acc1[t], 0, 0, 0);
    }
  }
  __syncthreads();  // all waves done reading Bs1 before HsW/Bs2 overwrite it

  // hidden -> A-fragments via per-wave LDS half-buffers (intra-wave, no barriers)
  short8 hf[8];
#pragma unroll
  for (int half = 0; half < 2; half++) {
#pragma unroll
    for (int t = 0; t < 8; t++) {
      int tt = half * 8 + t;
      int cg = tt * 16 + cn;
      int cl = t * 16 + cn;
      float bb = b1[cg];
#pragma unroll
      for (int i = 0; i < 4; i++) {
        int r = quad * 4 + i;
        HsW[r * LDHW + cl] = f2b(gelu_f(acc1[tt][i] + bb));
      }
    }
#pragma unroll
    for (int k0 = 0; k0 < 4; k0++)
      hf[half * 4 + k0] = *(const short8*)&HsW[mrow * LDHW + k0 * 32 + quad * 8];
  }

#pragma unroll
  for (int j = 0; j < 4; j++) {
    int chunk = j * 256 + tid;
    int n = chunk >> 3, k8 = (chunk & 7) * 8;
    *(short8*)&Bs2[n * LDK + k8] = *(const short8*)&W2T[(long)n * H2 + k8];
  }
  __syncthreads();

  floatx4 acc2[8];
#pragma unroll
  for (int t = 0; t < 8; t++) acc2[t] = (floatx4)0.f;

  for (int ks = 0; ks < 4; ks++) {
    if (ks > 0) {
      __syncthreads();
#pragma unroll
      for (int j = 0; j < 4; j++) {
        int chunk = j * 256 + tid;
        int n = chunk >> 3, k8 = (chunk & 7) * 8;
        *(short8*)&Bs2[n * LDK + k8] = *(const short8*)&W2T[(long)n * H2 + ks * 64 + k8];
      }
      __syncthreads();
    }
    int kk = ks * 2;
#pragma unroll
    for (int t = 0; t < 8; t++) {
      int kb0 = quad * 8;
      short8 bf0 = *(const short8*)&Bs2[(t * 16 + mrow) * LDK + kb0];
      acc2[t] = __builtin_amdgcn_mfma_f32_16x16x32_bf16(hf[kk], bf0, acc2[t], 0, 0, 0);
      short8 bf1 = *(const short8*)&Bs2[(t * 16 + mrow) * LDK + 32 + kb0];
      acc2[t] = __builtin_amdgcn_mfma_f32_16x16x32_bf16(hf[kk + 1], bf1, acc2[t], 0, 0, 0);
    }
  }

#pragma unroll
  for (int t = 0; t < 8; t++) {
    int c = t * 16 + cn;
    float bb = b2[c];
    float rsc = 0.f, rsh = 0.f;
    if (BNRES) { rsc = scsh[c]; rsh = scsh[H + c]; }
#pragma unroll
    for (int i = 0; i < 4; i++) {
      int r = row0 + w * 16 + quad * 4 + i;
      if (r < M) {
        long off = (long)r * H + c;
        float v = gelu_f(acc2[t][i] + bb);
        if (BNRES) v += C[off] * rsc + rsh;
        C[off] = v;
      }
    }
  }
}

// ---------------- persistent fused 2-layer FFN (in-loop: warm input, weights LDS-resident) ----------------
// 256 blocks x 1024 threads (1 block/CU, 16 waves). Stage W1+W2 once, then per-wave
// 16-row tiles with zero barriers. A-loads go DIRECTLY into pack8.
// Epilogue residual bn(x): recovered from the still-live af fragments via a scr
// transpose (same intra-wave ds_write->ds_read pattern as phase 1) — no C re-read.
template <int BNRES, int POOL>
__global__ __launch_bounds__(1024) void ffn_persist(const float* __restrict__ A,
                                                    const unsigned short* __restrict__ W1T, const float* __restrict__ b1,
                                                    const unsigned short* __restrict__ W2T, const float* __restrict__ b2,
                                                    const float* __restrict__ scsh,
                                                    float* __restrict__ C, float* __restrict__ pooled,
                                                    const int* __restrict__ batch, int M) {
  __shared__ unsigned short lds[78848];  // 157696 B
  int tid = threadIdx.x;
#pragma unroll
  for (int j = 0; j < 4; j++) {
    int idx = j * 1024 + tid;
    int n = idx >> 4, k8 = (idx & 15) * 8;
    *(short8*)&lds[n * 136 + k8] = *(const short8*)&W1T[n * 128 + k8];
  }
#pragma unroll
  for (int j = 0; j < 4; j++) {
    int idx = j * 1024 + tid;
    int n = idx >> 5, k8 = (idx & 31) * 8;
    *(short8*)&lds[34816 + n * 264 + k8] = *(const short8*)&W2T[n * 256 + k8];
  }
  __syncthreads();

  int lane = tid & 63, w = tid >> 6;
  int mrow = lane & 15, quad = lane >> 4, cn = lane & 15;
  unsigned short* scr = &lds[68608 + w * 640];
  int TT = (M + 15) >> 4;
  int stride = (int)(gridDim.x << 4);

  for (int tile = blockIdx.x * 16 + w; tile < TT; tile += stride) {
    int row0 = tile << 4;
    int arow = row0 + mrow;
    bool rin = arow < M;

    short8 af[4];
#pragma unroll
    for (int k0 = 0; k0 < 4; k0++) {
      int kb = k0 * 32 + quad * 8;
      floatx4 a0 = (floatx4)0.f, a1 = (floatx4)0.f;
      if (rin) {
        a0 = *(const floatx4*)&A[(long)arow * H + kb];
        a1 = *(const floatx4*)&A[(long)arow * H + kb + 4];
        if (BNRES) {
          a0 = a0 * *(const floatx4*)&scsh[kb] + *(const floatx4*)&scsh[H + kb];
          a1 = a1 * *(const floatx4*)&scsh[kb + 4] + *(const floatx4*)&scsh[H + kb + 4];
        }
      }
      af[k0] = pack8(a0, a1);
    }

    floatx4 acc2[8];
#pragma unroll
    for (int t = 0; t < 8; t++) acc2[t] = (floatx4)0.f;

#pragma unroll
    for (int p = 0; p < 8; p++) {
      // phase 1: hidden tiles t = 2p, 2p+1 (32 hidden cols), K=128
#pragma unroll
      for (int u = 0; u < 2; u++) {
        int t = p * 2 + u;
        floatx4 a = (floatx4)0.f;
#pragma unroll
        for (int k = 0; k < 4; k++) {
          short8 bf = *(const short8*)&lds[(t * 16 + mrow) * 136 + k * 32 + quad * 8];
          a = __builtin_amdgcn_mfma_f32_16x16x32_bf16(af[k], bf, a, 0, 0, 0);
        }
        float bb = b1[t * 16 + cn];
#pragma unroll
        for (int i = 0; i < 4; i++)
          scr[(quad * 4 + i) * 40 + u * 16 + cn] = f2b(gelu_f(a[i] + bb));
      }
      // transpose readback: A-frag for hidden k-chunk p (row=mrow, k=quad*8..+7)
      short8 hf = *(const short8*)&scr[mrow * 40 + quad * 8];
      // phase 2: accumulate this 32-k chunk into all 8 output col-tiles
#pragma unroll
      for (int ct = 0; ct < 8; ct++) {
        short8 bf = *(const short8*)&lds[34816 + (ct * 16 + mrow) * 264 + p * 32 + quad * 8];
        acc2[ct] = __builtin_amdgcn_mfma_f32_16x16x32_bf16(hf, bf, acc2[ct], 0, 0, 0);
      }
    }

    // epilogue (+ optional fused pooling); residual = transposed af (bn(x) bf16)
    int g0 = 0; bool same = true;
    if (POOL) {
      int rl = row0 + 15; if (rl >= M) rl = M - 1;
      g0 = batch[row0];
      same = (batch[rl] == g0);
    }
#pragma unroll
    for (int k0 = 0; k0 < 4; k0++) {
      // stage this 32-col chunk of bn(x): lane holds row mrow, cols k0*32+quad*8..+7
      *(short8*)&scr[mrow * 40 + quad * 8] = af[k0];
#pragma unroll
      for (int u = 0; u < 2; u++) {
        int t = k0 * 2 + u;
        int c = t * 16 + cn;
        float bb = b2[c];
        float s = 0.f;
#pragma unroll
        for (int i = 0; i < 4; i++) {
          int r = row0 + quad * 4 + i;
          float v = 0.f;
          if (r < M) {
            v = gelu_f(acc2[t][i] + bb);
            if (BNRES) v += b2f(scr[(quad * 4 + i) * 40 + u * 16 + cn]);
            C[(long)r * H + c] = v;
            if (POOL && !same) atomicAdd(&pooled[batch[r] * H + c], v);
          }
          s += v;
        }
        if (POOL && same) {
          s += __shfl_xor(s, 16);
          s += __shfl_xor(s, 32);
          if (quad == 0) atomicAdd(&pooled[g0 * H + c], s);
        }
      }
    }
  }
}

// ---------------- parallel 64-row MLP stages (vn / post) ----------------
template <int BN, int UVN>
__global__ __launch_bounds__(256) void mlp64_l1(const float* __restrict__ vn, const float* __restrict__ pooled,
                                                const float* __restrict__ counts,
                                                const float* __restrict__ W1, const float* __restrict__ b1,
                                                const float* __restrict__ g1, const float* __restrict__ be1,
                                                float* __restrict__ h1) {
  __shared__ float u[64 * H];
  __shared__ float red[8 * 64];
  int t = threadIdx.x;
  for (int idx = t; idx < 64 * H; idx += 256) {
    float v = pooled[idx];
    if (UVN) v = vn[idx] + v / fmaxf(counts[idx >> 7], 1.0f);
    u[idx] = v;
  }
  __syncthreads();
  int tc = t & 63, tg = t >> 6;
  int c = blockIdx.x * 64 + tc;
  float acc[16];
  float bj = b1[c];
#pragma unroll
  for (int g = 0; g < 16; g++) acc[g] = bj;
  for (int k0 = 0; k0 < H; k0 += 4) {
    float w0 = W1[(k0 + 0) * H2 + c];
    float w1 = W1[(k0 + 1) * H2 + c];
    float w2 = W1[(k0 + 2) * H2 + c];
    float w3 = W1[(k0 + 3) * H2 + c];
#pragma unroll
    for (int g = 0; g < 16; g++) {
      float4 v = *(const float4*)&u[(tg * 16 + g) * H + k0];
      acc[g] += v.x * w0 + v.y * w1 + v.z * w2 + v.w * w3;
    }
  }
  float sc = 1.f, sh = 0.f;
  if (BN) {
    float s = 0.f, s2 = 0.f;
#pragma unroll
    for (int g = 0; g < 16; g++) { s += acc[g]; s2 += acc[g] * acc[g]; }
    red[tg * 64 + tc] = s;
    red[256 + tg * 64 + tc] = s2;
    __syncthreads();
    float st = red[tc] + red[64 + tc] + red[128 + tc] + red[192 + tc];
    float st2 = red[256 + tc] + red[320 + tc] + red[384 + tc] + red[448 + tc];
    float m = st * (1.f / 64.f);
    float var = st2 * (1.f / 64.f) - m * m;
    sc = rsqrtf(var + 1e-5f) * g1[c];
    sh = be1[c] - m * sc;
  }
#pragma unroll
  for (int g = 0; g < 16; g++) h1[(tg * 16 + g) * H2 + c] = gelu_f(acc[g] * sc + sh);
}

template <int BN>
__global__ __launch_bounds__(256) void mlp64_l2(const float* __restrict__ h1,
                                                const float* __restrict__ W2, const float* __restrict__ b2,
                                                const float* __restrict__ g2, const float* __restrict__ be2,
                                                float* __restrict__ outp) {
  __shared__ float red[8 * 64];
  int t = threadIdx.x;
  int tc = t & 63, tg = t >> 6;
  int c = blockIdx.x * 64 + tc;
  float acc[16];
  float bj = b2[c];
#pragma unroll
  for (int g = 0; g < 16; g++) acc[g] = bj;
  for (int k0 = 0; k0 < H2; k0 += 4) {
    float w0 = W2[(k0 + 0) * H + c];
    float w1 = W2[(k0 + 1) * H + c];
    float w2 = W2[(k0 + 2) * H + c];
    float w3 = W2[(k0 + 3) * H + c];
#pragma unroll
    for (int g = 0; g < 16; g++) {
      float4 v = *(const float4*)&h1[(tg * 16 + g) * H2 + k0];
      acc[g] += v.x * w0 + v.y * w1 + v.z * w2 + v.w * w3;
    }
  }
  float sc = 1.f, sh = 0.f;
  if (BN) {
    float s = 0.f, s2 = 0.f;
#pragma unroll
    for (int g = 0; g < 16; g++) { s += acc[g]; s2 += acc[g] * acc[g]; }
    red[tg * 64 + tc] = s;
    red[256 + tg * 64 + tc] = s2;
    __syncthreads();
    float st = red[tc] + red[64 + tc] + red[128 + tc] + red[192 + tc];
    float st2 = red[256 + tc] + red[320 + tc] + red[384 + tc] + red[448 + tc];
    float m = st * (1.f / 64.f);
    float var = st2 * (1.f / 64.f) - m * m;
    sc = rsqrtf(var + 1e-5f) * g2[c];
    sh = be2[c] - m * sc;
  }
#pragma unroll
  for (int g = 0; g < 16; g++) outp[(tg * 16 + g) * H + c] = gelu_f(acc[g] * sc + sh);
}

// ---------------- host launch ----------------

extern "C" void kernel_launch(void* const* d_in, const int* in_sizes, int n_in,
                              void* d_out, int out_size, void* d_ws, size_t ws_size,
                              hipStream_t stream) {
  const float* x_in   = (const float*)d_in[0];
  const int*   edge   = (const int*)d_in[1];
  const int*   batch  = (const int*)d_in[2];
  const float* pre_W1 = (const float*)d_in[3];
  const float* pre_b1 = (const float*)d_in[4];
  const float* pre_W2 = (const float*)d_in[5];
  const float* pre_b2 = (const float*)d_in[6];
  const float* conv_W = (const float*)d_in[7];
  const float* conv_b = (const float*)d_in[8];
  const float* bn_g   = (const float*)d_in[9];
  const float* bn_b   = (const float*)d_in[10];
  const float* ffn_W1 = (const float*)d_in[11];
  const float* ffn_b1 = (const float*)d_in[12];
  const float* ffn_W2 = (const float*)d_in[13];
  const float* ffn_b2 = (const float*)d_in[14];
  const float* vn_W1  = (const float*)d_in[15];
  const float* vn_b1  = (const float*)d_in[16];
  const float* vn_g1  = (const float*)d_in[17];
  const float* vn_be1 = (const float*)d_in[18];
  const float* vn_W2  = (const float*)d_in[19];
  const float* vn_b2  = (const float*)d_in[20];
  const float* vn_g2  = (const float*)d_in[21];
  const float* vn_be2 = (const float*)d_in[22];
  const float* vn_emb = (const float*)d_in[23];
  const float* post_W1= (const float*)d_in[24];
  const float* post_b1= (const float*)d_in[25];
  const float* post_W2= (const float*)d_in[26];
  const float* post_b2= (const float*)d_in[27];
  float* out = (float*)d_out;

  const int N    = in_sizes[2];
  const int E    = in_sizes[1] / 2;
  const int G    = out_size / H;
  const int HOPS = in_sizes[7] / (H * H);
  const int NH   = N * H;

  // workspace layout
  float* w = (float*)d_ws;
  float* buf_x  = w;  w += NH;
  float* buf_t  = w;  w += N * H2;
  unsigned short* buf_h16 = (unsigned short*)buf_t;
  float* dinv   = w;  w += N;
  float* counts = w;  w += G;
  float* stats  = w;  w += 2 * H;
  float* scsh   = w;  w += 2 * H;
  float* pooled = w;  w += G * H;
  float* vn     = w;  w += G * H;
  float* mlp_h1 = w;  w += G * H2;
  float* csr_norm = w; w += E;
  int* iw = (int*)w;
  int* cnt      = iw;  iw += N;
  int* row_ptr  = iw;  iw += N + 1;
  int* cursor   = iw;  iw += N;
  int* csr_src  = iw;  iw += E;
  int* blockSum = iw;  iw += 1024;
  int* blockOff = iw;  iw += 1024;
  unsigned short* wt = (unsigned short*)iw;
  unsigned short* preW1T = wt;  wt += H * H2;
  unsigned short* preW2T = wt;  wt += H2 * H;
  unsigned short* convT  = wt;  wt += HOPS * H * H;
  unsigned short* ffn1T  = wt;  wt += HOPS * H * H2;
  unsigned short* ffn2T  = wt;  wt += HOPS * H2 * H;

  const int* src = edge;
  const int* dst = edge + E;

  int gE  = (E + 255) / 256;
  int gM  = (N + 63) / 64;
  int nb  = (N + 1023) / 1024;
  float invN = 1.0f / (float)N;

  // weight transposes
  transpose_w<<<(H * H2 + 255) / 256, 256, 0, stream>>>(pre_W1, preW1T, H, H2, H * H2);
  transpose_w<<<(H2 * H + 255) / 256, 256, 0, stream>>>(pre_W2, preW2T, H2, H, H2 * H);
  transpose_w<<<(HOPS * H * H + 255) / 256, 256, 0, stream>>>(conv_W, convT, H, H, HOPS * H * H);
  transpose_w<<<(HOPS * H * H2 + 255) / 256, 256, 0, stream>>>(ffn_W1, ffn1T, H, H2, HOPS * H * H2);
  transpose_w<<<(HOPS * H2 * H + 255) / 256, 256, 0, stream>>>(ffn_W2, ffn2T, H2, H, HOPS * H2 * H);

  // CSR build + dinv
  hipMemsetAsync(cnt, 0, N * sizeof(int), stream);
  hist_kernel<<<gE, 256, 0, stream>>>(cnt, dst, E);
  scan_a<<<nb, 256, 0, stream>>>(cnt, row_ptr, blockSum, dinv, N);
  scan_b<<<1, 1024, 0, stream>>>(blockSum, blockOff, nb, row_ptr, N, E);
  scan_c<<<nb, 256, 0, stream>>>(row_ptr, blockOff, N);
  hipMemsetAsync(cursor, 0, N * sizeof(int), stream);
  build_csr_kernel<<<gE, 256, 0, stream>>>(src, dst, row_ptr, cursor, dinv, csr_src, csr_norm, E);

  // graph counts, vn init
  hipMemsetAsync(counts, 0, G * sizeof(float), stream);
  count_kernel<<<(N + 256 * 16 - 1) / (256 * 16), 256, 0, stream>>>(counts, batch, N, G);
  vn_init_kernel<<<(G * H + 255) / 256, 256, 0, stream>>>(vn, vn_emb, G * H);

  // pre-FFNN: cold x_in -> many-block small-LDS variant (more memory parallelism)
  ffn_fused<0><<<gM, 256, 0, stream>>>(x_in, preW1T, pre_b1, preW2T, pre_b2, nullptr, buf_x, N);

  for (int i = 0; i < HOPS; i++) {
    // GCN: h16 = bf16( (x + vn[batch]) @ W ); block 0 zeroes stats for gather
    conv_gemm<<<gM, 256, 0, stream>>>(buf_x, convT + i * H * H, vn, batch, buf_h16, stats, N);
    // x = x + vn[batch] + bias + selfloop + gathered edges; BN stats fused
    gather_agg<<<(N + 31) / 32, 256, 0, stream>>>(buf_h16, csr_src, csr_norm, row_ptr, dinv, vn, batch,
                                                  conv_b + i * H, buf_x, stats, N);
    // stats -> scale/shift; also zeroes pooled for the ffn_persist POOL atomics
    bn_finalize_kernel<<<1, 128, 0, stream>>>(stats, bn_g + i * H, bn_b + i * H, scsh, invN, pooled, G * H);
    // fused FFN: x = gelu(gelu(bn(x)@W1+b1)@W2+b2) + bn(x); pooling fused into epilogue
    ffn_persist<1, 1><<<256, 1024, 0, stream>>>(buf_x, ffn1T + i * H * H2, ffn_b1 + i * H2,
                                                ffn2T + i * H2 * H, ffn_b2 + i * H, scsh,
                                                buf_x, pooled, batch, N);
    // virtual node update
    if (i < HOPS - 1) {
      mlp64_l1<1, 1><<<H2 / 64, 256, 0, stream>>>(vn, pooled, counts,
                                                  vn_W1 + i * H * H2, vn_b1 + i * H2, vn_g1 + i * H2, vn_be1 + i * H2,
                                                  mlp_h1);
      mlp64_l2<1><<<H / 64, 256, 0, stream>>>(mlp_h1, vn_W2 + i * H2 * H, vn_b2 + i * H, vn_g2 + i * H, vn_be2 + i * H, vn);
    }
  }

  // final global_add_pool came fused from the last ffn_persist; post-FFNN
  mlp64_l1<0, 0><<<H2 / 64, 256, 0, stream>>>(nullptr, pooled, nullptr, post_W1, post_b1, nullptr, nullptr, mlp_h1);
  mlp64_l2<0><<<H / 64, 256, 0, stream>>>(mlp_h1, post_W2, post_b2, nullptr, nullptr, out);
}